// Round 2
// baseline (658.646 us; speedup 1.0000x reference)
//
#include <hip/hip_runtime.h>

#define D 128
#define BM 64
#define BK 32

// ---------------- dtype detection: int64 vs int32 edge_index ----------------
__global__ void k_detect64(const int* __restrict__ ei32, int* __restrict__ flag) {
    __shared__ int nz;
    if (threadIdx.x == 0) nz = 0;
    __syncthreads();
    int c = 0;
    for (int i = threadIdx.x; i < 1024; i += blockDim.x) {
        if (ei32[2 * i + 1] != 0) c++;   // int64 layout: high words all 0
    }
    atomicAdd(&nz, c);
    __syncthreads();
    if (threadIdx.x == 0) *flag = (nz == 0) ? 1 : 0;  // 1 => int64
}

__device__ __forceinline__ int e_src(const void* ei, int e, int is64, int E) {
    return is64 ? (int)((const long long*)ei)[e] : ((const int*)ei)[e];
}
__device__ __forceinline__ int e_dst(const void* ei, int e, int is64, int E) {
    return is64 ? (int)((const long long*)ei)[E + e] : ((const int*)ei)[E + e];
}

// ---------------- graph build ----------------
__global__ void k_zero(int* __restrict__ p, int n) {
    int i = blockIdx.x * blockDim.x + threadIdx.x;
    if (i < n) p[i] = 0;
}

__global__ void k_hist(const void* __restrict__ ei, int E, const int* __restrict__ flag,
                       int* __restrict__ cnt) {
    int is64 = *flag;
    for (int e = blockIdx.x * blockDim.x + threadIdx.x; e < E; e += gridDim.x * blockDim.x) {
        atomicAdd(&cnt[e_dst(ei, e, is64, E)], 1);
    }
}

__global__ __launch_bounds__(1024) void k_scan_build(const int* __restrict__ cnt,
        int* __restrict__ row_start, int* __restrict__ cursor, float* __restrict__ dinv,
        int N, int E) {
    __shared__ int part[1024];
    int t = threadIdx.x;
    int chunk = (N + 1023) >> 10;
    int lo = t * chunk, hi = min(lo + chunk, N);
    int s = 0;
    for (int i = lo; i < hi; ++i) s += cnt[i];
    part[t] = s;
    __syncthreads();
    for (int d = 1; d < 1024; d <<= 1) {
        int v = (t >= d) ? part[t - d] : 0;
        __syncthreads();
        part[t] += v;
        __syncthreads();
    }
    int run = part[t] - s;  // exclusive prefix
    for (int i = lo; i < hi; ++i) {
        row_start[i] = run;
        cursor[i] = run;
        dinv[i] = rsqrtf((float)(cnt[i] + 1));   // +1 self-loop; always > 0
        run += cnt[i];
    }
    if (t == 0) row_start[N] = E;
}

__global__ void k_scatter(const void* __restrict__ ei, int E, const int* __restrict__ flag,
                          int* __restrict__ cursor, int* __restrict__ esrc) {
    int is64 = *flag;
    for (int e = blockIdx.x * blockDim.x + threadIdx.x; e < E; e += gridDim.x * blockDim.x) {
        int s = e_src(ei, e, is64, E);
        int d = e_dst(ei, e, is64, E);
        int pos = atomicAdd(&cursor[d], 1);
        esrc[pos] = s;
    }
}

// ---------------- GEMM: h = x @ W  (N x 128) @ (128 x 128), fp32 ----------------
__global__ __launch_bounds__(256) void k_gemm(const float* __restrict__ x,
        const float* __restrict__ W, float* __restrict__ h, int N) {
    __shared__ float As[BM][BK + 4];   // stride 36 floats: 16B-aligned rows, broadcast reads
    __shared__ float Bs[BK][D];
    int tid = threadIdx.x;
    int br = blockIdx.x * BM;
    int r0 = (tid >> 5) * 8;   // 8 row-groups of 8
    int c0 = (tid & 31) * 4;   // 32 col-groups of 4
    float4 acc[8];
#pragma unroll
    for (int j = 0; j < 8; ++j) acc[j] = make_float4(0.f, 0.f, 0.f, 0.f);

    for (int kt = 0; kt < D; kt += BK) {
        // stage A tile (64x32)
        {
            int r = tid >> 3;
            int kc = (tid & 7) * 4;
#pragma unroll
            for (int half = 0; half < 2; ++half) {
                int rr = r + half * 32;
                int gr = br + rr;
                float4 v = make_float4(0.f, 0.f, 0.f, 0.f);
                if (gr < N) v = *(const float4*)&x[(long)gr * D + kt + kc];
                *(float4*)&As[rr][kc] = v;
            }
        }
        // stage B tile (32x128)
#pragma unroll
        for (int q = 0; q < 4; ++q) {
            int id = tid + q * 256;
            int krow = id >> 5;
            int cc = (id & 31) * 4;
            *(float4*)&Bs[krow][cc] = *(const float4*)&W[(long)(kt + krow) * D + cc];
        }
        __syncthreads();
#pragma unroll
        for (int k = 0; k < BK; k += 4) {
            float4 b0 = *(const float4*)&Bs[k + 0][c0];
            float4 b1 = *(const float4*)&Bs[k + 1][c0];
            float4 b2 = *(const float4*)&Bs[k + 2][c0];
            float4 b3 = *(const float4*)&Bs[k + 3][c0];
#pragma unroll
            for (int j = 0; j < 8; ++j) {
                float4 a = *(const float4*)&As[r0 + j][k];
                acc[j].x += a.x * b0.x + a.y * b1.x + a.z * b2.x + a.w * b3.x;
                acc[j].y += a.x * b0.y + a.y * b1.y + a.z * b2.y + a.w * b3.y;
                acc[j].z += a.x * b0.z + a.y * b1.z + a.z * b2.z + a.w * b3.z;
                acc[j].w += a.x * b0.w + a.y * b1.w + a.z * b2.w + a.w * b3.w;
            }
        }
        __syncthreads();
    }
#pragma unroll
    for (int j = 0; j < 8; ++j) {
        int gr = br + r0 + j;
        if (gr < N) *(float4*)&h[(long)gr * D + c0] = acc[j];
    }
}

// ---------------- aggregation: out = relu(segsum(h[src]*norm) + self + bias) ---------
__global__ __launch_bounds__(256) void k_agg(const float* __restrict__ h,
        const int* __restrict__ row_start, const int* __restrict__ esrc,
        const float* __restrict__ dinv, const float* __restrict__ bias,
        float* __restrict__ out, int N) {
    int wid = (blockIdx.x * blockDim.x + threadIdx.x) >> 6;
    int lane = threadIdx.x & 63;
    if (wid >= N) return;
    int i = wid;
    float di = dinv[i];
    const float2* hv = (const float2*)h;
    int j0 = row_start[i], j1 = row_start[i + 1];

    float2 acc = hv[(long)i * 64 + lane];   // self-loop: h[i]*dinv[i]^2
    float dii = di * di;
    acc.x *= dii;
    acc.y *= dii;

    int j = j0;
    int sn = (j < j1) ? esrc[j] : 0;
    while (j < j1) {
        int s = sn;
        ++j;
        sn = (j < j1) ? esrc[j] : 0;
        float nm = dinv[s] * di;
        float2 hs = hv[(long)s * 64 + lane];
        acc.x = fmaf(hs.x, nm, acc.x);
        acc.y = fmaf(hs.y, nm, acc.y);
    }
    float2 bv = ((const float2*)bias)[lane];
    acc.x = fmaxf(acc.x + bv.x, 0.f);
    acc.y = fmaxf(acc.y + bv.y, 0.f);
    ((float2*)out)[(long)i * 64 + lane] = acc;
}

// ---------------- host launch ----------------
extern "C" void kernel_launch(void* const* d_in, const int* in_sizes, int n_in,
                              void* d_out, int out_size, void* d_ws, size_t ws_size,
                              hipStream_t stream) {
    const float* x  = (const float*)d_in[0];
    const void*  ei = d_in[1];
    const float* W0 = (const float*)d_in[2];
    const float* b0 = (const float*)d_in[3];
    const float* W1 = (const float*)d_in[4];
    const float* b1 = (const float*)d_in[5];
    const float* W2 = (const float*)d_in[6];
    const float* b2 = (const float*)d_in[7];
    float* out = (float*)d_out;

    const int N = in_sizes[0] / D;       // 50000
    const int E = in_sizes[1] / 2;       // 800000

    // workspace layout (256B aligned)
    char* ws = (char*)d_ws;
    size_t off = 0;
    auto alloc = [&](size_t bytes) {
        char* p = ws + off;
        off = (off + bytes + 255) & ~(size_t)255;
        return p;
    };
    int*   flag      = (int*)alloc(4);
    int*   cnt       = (int*)alloc((size_t)N * 4);
    int*   row_start = (int*)alloc((size_t)(N + 1) * 4);
    int*   cursor    = (int*)alloc((size_t)N * 4);
    float* dinv      = (float*)alloc((size_t)N * 4);
    int*   esrc      = (int*)alloc((size_t)E * 4);
    float* hbuf      = (float*)alloc((size_t)N * D * 4);
    (void)ws_size;

    // graph build
    k_detect64<<<1, 256, 0, stream>>>((const int*)ei, flag);
    k_zero<<<(N + 255) / 256, 256, 0, stream>>>(cnt, N);
    k_hist<<<2048, 256, 0, stream>>>(ei, E, flag, cnt);
    k_scan_build<<<1, 1024, 0, stream>>>(cnt, row_start, cursor, dinv, N, E);
    k_scatter<<<2048, 256, 0, stream>>>(ei, E, flag, cursor, esrc);

    const int gemm_grid = (N + BM - 1) / BM;
    const int agg_grid  = (N + 3) / 4;   // 4 waves per 256-thread block

    // layer 0: x -> hbuf -> d_out
    k_gemm<<<gemm_grid, 256, 0, stream>>>(x, W0, hbuf, N);
    k_agg<<<agg_grid, 256, 0, stream>>>(hbuf, row_start, esrc, dinv, b0, out, N);
    // layer 1: d_out -> hbuf -> d_out
    k_gemm<<<gemm_grid, 256, 0, stream>>>(out, W1, hbuf, N);
    k_agg<<<agg_grid, 256, 0, stream>>>(hbuf, row_start, esrc, dinv, b1, out, N);
    // layer 2
    k_gemm<<<gemm_grid, 256, 0, stream>>>(out, W2, hbuf, N);
    k_agg<<<agg_grid, 256, 0, stream>>>(hbuf, row_start, esrc, dinv, b2, out, N);
}

// Round 3
// 533.567 us; speedup vs baseline: 1.2344x; 1.2344x over previous
//
#include <hip/hip_runtime.h>

#define D 128
#define BM 64
#define BK 32
#define SCAN_B 256

// ---------------- dtype detection: int64 vs int32 edge_index ----------------
__global__ void k_detect64(const int* __restrict__ ei32, int* __restrict__ flag) {
    __shared__ int nz;
    if (threadIdx.x == 0) nz = 0;
    __syncthreads();
    int c = 0;
    for (int i = threadIdx.x; i < 1024; i += blockDim.x) {
        if (ei32[2 * i + 1] != 0) c++;   // int64 layout: high words all 0
    }
    atomicAdd(&nz, c);
    __syncthreads();
    if (threadIdx.x == 0) *flag = (nz == 0) ? 1 : 0;  // 1 => int64
}

__device__ __forceinline__ int e_src(const void* ei, int e, int is64, int E) {
    return is64 ? (int)((const long long*)ei)[e] : ((const int*)ei)[e];
}
__device__ __forceinline__ int e_dst(const void* ei, int e, int is64, int E) {
    return is64 ? (int)((const long long*)ei)[E + e] : ((const int*)ei)[E + e];
}

// ---------------- graph build ----------------
__global__ void k_hist(const void* __restrict__ ei, int E, const int* __restrict__ flag,
                       int* __restrict__ cnt) {
    int is64 = *flag;
    for (int e = blockIdx.x * blockDim.x + threadIdx.x; e < E; e += gridDim.x * blockDim.x) {
        atomicAdd(&cnt[e_dst(ei, e, is64, E)], 1);
    }
}

// 3-phase parallel exclusive scan over cnt[N]
__global__ __launch_bounds__(SCAN_B) void k_block_sum(const int* __restrict__ cnt,
                                                      int* __restrict__ partial, int N) {
    __shared__ int sh[SCAN_B];
    int i = blockIdx.x * SCAN_B + threadIdx.x;
    sh[threadIdx.x] = (i < N) ? cnt[i] : 0;
    __syncthreads();
#pragma unroll
    for (int d = SCAN_B / 2; d > 0; d >>= 1) {
        if (threadIdx.x < d) sh[threadIdx.x] += sh[threadIdx.x + d];
        __syncthreads();
    }
    if (threadIdx.x == 0) partial[blockIdx.x] = sh[0];
}

__global__ __launch_bounds__(SCAN_B) void k_scan_partials(int* __restrict__ partial, int nb) {
    // single block; nb <= SCAN_B
    __shared__ int sh[SCAN_B];
    int v = (threadIdx.x < nb) ? partial[threadIdx.x] : 0;
    sh[threadIdx.x] = v;
    __syncthreads();
#pragma unroll
    for (int d = 1; d < SCAN_B; d <<= 1) {
        int t = (threadIdx.x >= d) ? sh[threadIdx.x - d] : 0;
        __syncthreads();
        sh[threadIdx.x] += t;
        __syncthreads();
    }
    if (threadIdx.x < nb) partial[threadIdx.x] = sh[threadIdx.x] - v;  // exclusive
}

__global__ __launch_bounds__(SCAN_B) void k_finalize(const int* __restrict__ cnt,
        const int* __restrict__ partial, int* __restrict__ row_start,
        int* __restrict__ cursor, float* __restrict__ dinv, int N, int E) {
    __shared__ int sh[SCAN_B];
    int i = blockIdx.x * SCAN_B + threadIdx.x;
    int v = (i < N) ? cnt[i] : 0;
    sh[threadIdx.x] = v;
    __syncthreads();
#pragma unroll
    for (int d = 1; d < SCAN_B; d <<= 1) {
        int t = (threadIdx.x >= d) ? sh[threadIdx.x - d] : 0;
        __syncthreads();
        sh[threadIdx.x] += t;
        __syncthreads();
    }
    if (i < N) {
        int excl = sh[threadIdx.x] - v + partial[blockIdx.x];
        row_start[i] = excl;
        cursor[i]    = excl;
        dinv[i]      = rsqrtf((float)(v + 1));   // +1 self-loop; always > 0
    }
    if (i == 0) row_start[N] = E;
}

__global__ void k_scatter(const void* __restrict__ ei, int E, const int* __restrict__ flag,
                          int* __restrict__ cursor, int* __restrict__ esrc) {
    int is64 = *flag;
    for (int e = blockIdx.x * blockDim.x + threadIdx.x; e < E; e += gridDim.x * blockDim.x) {
        int s = e_src(ei, e, is64, E);
        int d = e_dst(ei, e, is64, E);
        int pos = atomicAdd(&cursor[d], 1);
        esrc[pos] = s;
    }
}

// ---------------- GEMM: h = x @ W  (N x 128) @ (128 x 128), fp32 ----------------
__global__ __launch_bounds__(256) void k_gemm(const float* __restrict__ x,
        const float* __restrict__ W, float* __restrict__ h, int N) {
    __shared__ float As[BM][BK + 4];   // stride 36 floats: 16B-aligned rows, broadcast reads
    __shared__ float Bs[BK][D];
    int tid = threadIdx.x;
    int br = blockIdx.x * BM;
    int r0 = (tid >> 5) * 8;   // 8 row-groups of 8
    int c0 = (tid & 31) * 4;   // 32 col-groups of 4
    float4 acc[8];
#pragma unroll
    for (int j = 0; j < 8; ++j) acc[j] = make_float4(0.f, 0.f, 0.f, 0.f);

    for (int kt = 0; kt < D; kt += BK) {
        // stage A tile (64x32)
        {
            int r = tid >> 3;
            int kc = (tid & 7) * 4;
#pragma unroll
            for (int half = 0; half < 2; ++half) {
                int rr = r + half * 32;
                int gr = br + rr;
                float4 v = make_float4(0.f, 0.f, 0.f, 0.f);
                if (gr < N) v = *(const float4*)&x[(long)gr * D + kt + kc];
                *(float4*)&As[rr][kc] = v;
            }
        }
        // stage B tile (32x128)
#pragma unroll
        for (int q = 0; q < 4; ++q) {
            int id = tid + q * 256;
            int krow = id >> 5;
            int cc = (id & 31) * 4;
            *(float4*)&Bs[krow][cc] = *(const float4*)&W[(long)(kt + krow) * D + cc];
        }
        __syncthreads();
#pragma unroll
        for (int k = 0; k < BK; k += 4) {
            float4 b0 = *(const float4*)&Bs[k + 0][c0];
            float4 b1 = *(const float4*)&Bs[k + 1][c0];
            float4 b2 = *(const float4*)&Bs[k + 2][c0];
            float4 b3 = *(const float4*)&Bs[k + 3][c0];
#pragma unroll
            for (int j = 0; j < 8; ++j) {
                float4 a = *(const float4*)&As[r0 + j][k];
                acc[j].x += a.x * b0.x + a.y * b1.x + a.z * b2.x + a.w * b3.x;
                acc[j].y += a.x * b0.y + a.y * b1.y + a.z * b2.y + a.w * b3.y;
                acc[j].z += a.x * b0.z + a.y * b1.z + a.z * b2.z + a.w * b3.z;
                acc[j].w += a.x * b0.w + a.y * b1.w + a.z * b2.w + a.w * b3.w;
            }
        }
        __syncthreads();
    }
#pragma unroll
    for (int j = 0; j < 8; ++j) {
        int gr = br + r0 + j;
        if (gr < N) *(float4*)&h[(long)gr * D + c0] = acc[j];
    }
}

// ---------------- aggregation: out = relu(segsum(h[src]*norm) + self + bias) ---------
__global__ __launch_bounds__(256) void k_agg(const float* __restrict__ h,
        const int* __restrict__ row_start, const int* __restrict__ esrc,
        const float* __restrict__ dinv, const float* __restrict__ bias,
        float* __restrict__ out, int N) {
    int wid = (blockIdx.x * blockDim.x + threadIdx.x) >> 6;
    int lane = threadIdx.x & 63;
    if (wid >= N) return;
    int i = wid;
    float di = dinv[i];
    const float2* hv = (const float2*)h;
    int j0 = row_start[i], j1 = row_start[i + 1];

    float2 acc = hv[(long)i * 64 + lane];   // self-loop: h[i]*dinv[i]^2
    float dii = di * di;
    acc.x *= dii;
    acc.y *= dii;

    int j = j0;
    int sn = (j < j1) ? esrc[j] : 0;
    while (j < j1) {
        int s = sn;
        ++j;
        sn = (j < j1) ? esrc[j] : 0;
        float nm = dinv[s] * di;
        float2 hs = hv[(long)s * 64 + lane];
        acc.x = fmaf(hs.x, nm, acc.x);
        acc.y = fmaf(hs.y, nm, acc.y);
    }
    float2 bv = ((const float2*)bias)[lane];
    acc.x = fmaxf(acc.x + bv.x, 0.f);
    acc.y = fmaxf(acc.y + bv.y, 0.f);
    ((float2*)out)[(long)i * 64 + lane] = acc;
}

// ---------------- host launch ----------------
extern "C" void kernel_launch(void* const* d_in, const int* in_sizes, int n_in,
                              void* d_out, int out_size, void* d_ws, size_t ws_size,
                              hipStream_t stream) {
    const float* x  = (const float*)d_in[0];
    const void*  ei = d_in[1];
    const float* W0 = (const float*)d_in[2];
    const float* b0 = (const float*)d_in[3];
    const float* W1 = (const float*)d_in[4];
    const float* b1 = (const float*)d_in[5];
    const float* W2 = (const float*)d_in[6];
    const float* b2 = (const float*)d_in[7];
    float* out = (float*)d_out;

    const int N = in_sizes[0] / D;       // 50000
    const int E = in_sizes[1] / 2;       // 800000

    // workspace layout (256B aligned)
    char* ws = (char*)d_ws;
    size_t off = 0;
    auto alloc = [&](size_t bytes) {
        char* p = ws + off;
        off = (off + bytes + 255) & ~(size_t)255;
        return p;
    };
    int*   flag      = (int*)alloc(4);
    int*   cnt       = (int*)alloc((size_t)N * 4);
    int*   row_start = (int*)alloc((size_t)(N + 1) * 4);
    int*   cursor    = (int*)alloc((size_t)N * 4);
    float* dinv      = (float*)alloc((size_t)N * 4);
    int*   partial   = (int*)alloc((size_t)SCAN_B * 4);
    int*   esrc      = (int*)alloc((size_t)E * 4);
    float* hbuf      = (float*)alloc((size_t)N * D * 4);
    (void)ws_size;

    const int nb = (N + SCAN_B - 1) / SCAN_B;   // 196 <= SCAN_B

    // graph build
    k_detect64<<<1, 256, 0, stream>>>((const int*)ei, flag);
    hipMemsetAsync(cnt, 0, (size_t)N * 4, stream);
    k_hist<<<2048, 256, 0, stream>>>(ei, E, flag, cnt);
    k_block_sum<<<nb, SCAN_B, 0, stream>>>(cnt, partial, N);
    k_scan_partials<<<1, SCAN_B, 0, stream>>>(partial, nb);
    k_finalize<<<nb, SCAN_B, 0, stream>>>(cnt, partial, row_start, cursor, dinv, N, E);
    k_scatter<<<2048, 256, 0, stream>>>(ei, E, flag, cursor, esrc);

    const int gemm_grid = (N + BM - 1) / BM;
    const int agg_grid  = (N + 3) / 4;   // 4 waves per 256-thread block

    // layer 0: x -> hbuf -> d_out
    k_gemm<<<gemm_grid, 256, 0, stream>>>(x, W0, hbuf, N);
    k_agg<<<agg_grid, 256, 0, stream>>>(hbuf, row_start, esrc, dinv, b0, out, N);
    // layer 1: d_out -> hbuf -> d_out
    k_gemm<<<gemm_grid, 256, 0, stream>>>(out, W1, hbuf, N);
    k_agg<<<agg_grid, 256, 0, stream>>>(hbuf, row_start, esrc, dinv, b1, out, N);
    // layer 2
    k_gemm<<<gemm_grid, 256, 0, stream>>>(out, W2, hbuf, N);
    k_agg<<<agg_grid, 256, 0, stream>>>(hbuf, row_start, esrc, dinv, b2, out, N);
}

// Round 4
// 395.287 us; speedup vs baseline: 1.6662x; 1.3498x over previous
//
#include <hip/hip_runtime.h>
#include <hip/hip_fp16.h>

#define D 128
#define BM 64
#define BK 32
#define SCAN_B 256

// ---------------- dtype detection: int64 vs int32 edge_index ----------------
__global__ void k_detect64(const int* __restrict__ ei32, int* __restrict__ flag) {
    __shared__ int nz;
    if (threadIdx.x == 0) nz = 0;
    __syncthreads();
    int c = 0;
    for (int i = threadIdx.x; i < 1024; i += blockDim.x) {
        if (ei32[2 * i + 1] != 0) c++;   // int64 layout: high words all 0
    }
    atomicAdd(&nz, c);
    __syncthreads();
    if (threadIdx.x == 0) *flag = (nz == 0) ? 1 : 0;  // 1 => int64
}

__device__ __forceinline__ int e_src(const void* ei, int e, int is64, int E) {
    return is64 ? (int)((const long long*)ei)[e] : ((const int*)ei)[e];
}
__device__ __forceinline__ int e_dst(const void* ei, int e, int is64, int E) {
    return is64 ? (int)((const long long*)ei)[E + e] : ((const int*)ei)[E + e];
}

// ---------------- graph build ----------------
__global__ void k_hist(const void* __restrict__ ei, int E, const int* __restrict__ flag,
                       int* __restrict__ cnt) {
    int is64 = *flag;
    for (int e = blockIdx.x * blockDim.x + threadIdx.x; e < E; e += gridDim.x * blockDim.x) {
        atomicAdd(&cnt[e_dst(ei, e, is64, E)], 1);
    }
}

// 3-phase parallel exclusive scan over cnt[N]
__global__ __launch_bounds__(SCAN_B) void k_block_sum(const int* __restrict__ cnt,
                                                      int* __restrict__ partial, int N) {
    __shared__ int sh[SCAN_B];
    int i = blockIdx.x * SCAN_B + threadIdx.x;
    sh[threadIdx.x] = (i < N) ? cnt[i] : 0;
    __syncthreads();
#pragma unroll
    for (int d = SCAN_B / 2; d > 0; d >>= 1) {
        if (threadIdx.x < d) sh[threadIdx.x] += sh[threadIdx.x + d];
        __syncthreads();
    }
    if (threadIdx.x == 0) partial[blockIdx.x] = sh[0];
}

__global__ __launch_bounds__(SCAN_B) void k_scan_partials(int* __restrict__ partial, int nb) {
    __shared__ int sh[SCAN_B];
    int v = (threadIdx.x < nb) ? partial[threadIdx.x] : 0;
    sh[threadIdx.x] = v;
    __syncthreads();
#pragma unroll
    for (int d = 1; d < SCAN_B; d <<= 1) {
        int t = (threadIdx.x >= d) ? sh[threadIdx.x - d] : 0;
        __syncthreads();
        sh[threadIdx.x] += t;
        __syncthreads();
    }
    if (threadIdx.x < nb) partial[threadIdx.x] = sh[threadIdx.x] - v;  // exclusive
}

__global__ __launch_bounds__(SCAN_B) void k_finalize(const int* __restrict__ cnt,
        const int* __restrict__ partial, int* __restrict__ row_start,
        int* __restrict__ cursor, float* __restrict__ dinv, int N, int E) {
    __shared__ int sh[SCAN_B];
    int i = blockIdx.x * SCAN_B + threadIdx.x;
    int v = (i < N) ? cnt[i] : 0;
    sh[threadIdx.x] = v;
    __syncthreads();
#pragma unroll
    for (int d = 1; d < SCAN_B; d <<= 1) {
        int t = (threadIdx.x >= d) ? sh[threadIdx.x - d] : 0;
        __syncthreads();
        sh[threadIdx.x] += t;
        __syncthreads();
    }
    if (i < N) {
        int excl = sh[threadIdx.x] - v + partial[blockIdx.x];
        row_start[i] = excl;
        cursor[i]    = excl;
        dinv[i]      = rsqrtf((float)(v + 1));   // +1 self-loop; always > 0
    }
    if (i == 0) row_start[N] = E;
}

__global__ void k_scatter(const void* __restrict__ ei, int E, const int* __restrict__ flag,
                          int* __restrict__ cursor, int* __restrict__ esrc) {
    int is64 = *flag;
    for (int e = blockIdx.x * blockDim.x + threadIdx.x; e < E; e += gridDim.x * blockDim.x) {
        int s = e_src(ei, e, is64, E);
        int d = e_dst(ei, e, is64, E);
        int pos = atomicAdd(&cursor[d], 1);
        esrc[pos] = s;
    }
}

// ------- GEMM: h' = (x @ W) * dinv[row], stored fp16  (N x 128)x(128 x 128) -------
__global__ __launch_bounds__(256) void k_gemm(const float* __restrict__ x,
        const float* __restrict__ W, const float* __restrict__ dinv,
        __half* __restrict__ h, int N) {
    __shared__ float As[BM][BK + 4];
    __shared__ float Bs[BK][D];
    int tid = threadIdx.x;
    int br = blockIdx.x * BM;
    int r0 = (tid >> 5) * 8;   // 8 row-groups of 8
    int c0 = (tid & 31) * 4;   // 32 col-groups of 4
    float4 acc[8];
#pragma unroll
    for (int j = 0; j < 8; ++j) acc[j] = make_float4(0.f, 0.f, 0.f, 0.f);

    for (int kt = 0; kt < D; kt += BK) {
        {
            int r = tid >> 3;
            int kc = (tid & 7) * 4;
#pragma unroll
            for (int half_ = 0; half_ < 2; ++half_) {
                int rr = r + half_ * 32;
                int gr = br + rr;
                float4 v = make_float4(0.f, 0.f, 0.f, 0.f);
                if (gr < N) v = *(const float4*)&x[(long)gr * D + kt + kc];
                *(float4*)&As[rr][kc] = v;
            }
        }
#pragma unroll
        for (int q = 0; q < 4; ++q) {
            int id = tid + q * 256;
            int krow = id >> 5;
            int cc = (id & 31) * 4;
            *(float4*)&Bs[krow][cc] = *(const float4*)&W[(long)(kt + krow) * D + cc];
        }
        __syncthreads();
#pragma unroll
        for (int k = 0; k < BK; k += 4) {
            float4 b0 = *(const float4*)&Bs[k + 0][c0];
            float4 b1 = *(const float4*)&Bs[k + 1][c0];
            float4 b2 = *(const float4*)&Bs[k + 2][c0];
            float4 b3 = *(const float4*)&Bs[k + 3][c0];
#pragma unroll
            for (int j = 0; j < 8; ++j) {
                float4 a = *(const float4*)&As[r0 + j][k];
                acc[j].x += a.x * b0.x + a.y * b1.x + a.z * b2.x + a.w * b3.x;
                acc[j].y += a.x * b0.y + a.y * b1.y + a.z * b2.y + a.w * b3.y;
                acc[j].z += a.x * b0.z + a.y * b1.z + a.z * b2.z + a.w * b3.z;
                acc[j].w += a.x * b0.w + a.y * b1.w + a.z * b2.w + a.w * b3.w;
            }
        }
        __syncthreads();
    }
#pragma unroll
    for (int j = 0; j < 8; ++j) {
        int gr = br + r0 + j;
        if (gr < N) {
            float sc = dinv[gr];
            union { __half2 h2[2]; uint2 u; } pk;
            pk.h2[0] = __floats2half2_rn(acc[j].x * sc, acc[j].y * sc);
            pk.h2[1] = __floats2half2_rn(acc[j].z * sc, acc[j].w * sc);
            *(uint2*)&h[(long)gr * D + c0] = pk.u;
        }
    }
}

// ------ aggregation: out = relu(dinv[i]*(sum_{s in N(i)} h'[s] + h'[i]) + bias) ------
__global__ __launch_bounds__(256) void k_agg(const __half* __restrict__ h,
        const int* __restrict__ row_start, const int* __restrict__ esrc,
        const float* __restrict__ dinv, const float* __restrict__ bias,
        float* __restrict__ out, int N) {
    int wid = (blockIdx.x * blockDim.x + threadIdx.x) >> 6;
    int lane = threadIdx.x & 63;
    if (wid >= N) return;
    int i = wid;
    float di = dinv[i];
    const __half2* hv = (const __half2*)h;   // 64 half2 per row (128 cols)
    int j0 = row_start[i], j1 = row_start[i + 1];

    float2 f = __half22float2(hv[(long)i * 64 + lane]);   // self-loop term h'[i]
    float accx = f.x, accy = f.y;

    int j = j0;
    for (; j + 4 <= j1; j += 4) {
        int s0 = esrc[j], s1 = esrc[j + 1], s2 = esrc[j + 2], s3 = esrc[j + 3];
        float2 f0 = __half22float2(hv[(long)s0 * 64 + lane]);
        float2 f1 = __half22float2(hv[(long)s1 * 64 + lane]);
        float2 f2 = __half22float2(hv[(long)s2 * 64 + lane]);
        float2 f3 = __half22float2(hv[(long)s3 * 64 + lane]);
        accx += (f0.x + f1.x) + (f2.x + f3.x);
        accy += (f0.y + f1.y) + (f2.y + f3.y);
    }
    for (; j < j1; ++j) {
        int s = esrc[j];
        float2 fs = __half22float2(hv[(long)s * 64 + lane]);
        accx += fs.x;
        accy += fs.y;
    }
    float2 bv = ((const float2*)bias)[lane];
    float2 o;
    o.x = fmaxf(fmaf(accx, di, bv.x), 0.f);
    o.y = fmaxf(fmaf(accy, di, bv.y), 0.f);
    ((float2*)out)[(long)i * 64 + lane] = o;
}

// ---------------- host launch ----------------
extern "C" void kernel_launch(void* const* d_in, const int* in_sizes, int n_in,
                              void* d_out, int out_size, void* d_ws, size_t ws_size,
                              hipStream_t stream) {
    const float* x  = (const float*)d_in[0];
    const void*  ei = d_in[1];
    const float* W0 = (const float*)d_in[2];
    const float* b0 = (const float*)d_in[3];
    const float* W1 = (const float*)d_in[4];
    const float* b1 = (const float*)d_in[5];
    const float* W2 = (const float*)d_in[6];
    const float* b2 = (const float*)d_in[7];
    float* out = (float*)d_out;

    const int N = in_sizes[0] / D;       // 50000
    const int E = in_sizes[1] / 2;       // 800000

    char* ws = (char*)d_ws;
    size_t off = 0;
    auto alloc = [&](size_t bytes) {
        char* p = ws + off;
        off = (off + bytes + 255) & ~(size_t)255;
        return p;
    };
    int*    flag      = (int*)alloc(4);
    int*    cnt       = (int*)alloc((size_t)N * 4);
    int*    row_start = (int*)alloc((size_t)(N + 1) * 4);
    int*    cursor    = (int*)alloc((size_t)N * 4);
    float*  dinv      = (float*)alloc((size_t)N * 4);
    int*    partial   = (int*)alloc((size_t)SCAN_B * 4);
    int*    esrc      = (int*)alloc((size_t)E * 4);
    __half* hbuf      = (__half*)alloc((size_t)N * D * 2);
    (void)ws_size;

    const int nb = (N + SCAN_B - 1) / SCAN_B;   // 196 <= SCAN_B

    // graph build
    k_detect64<<<1, 256, 0, stream>>>((const int*)ei, flag);
    hipMemsetAsync(cnt, 0, (size_t)N * 4, stream);
    k_hist<<<2048, 256, 0, stream>>>(ei, E, flag, cnt);
    k_block_sum<<<nb, SCAN_B, 0, stream>>>(cnt, partial, N);
    k_scan_partials<<<1, SCAN_B, 0, stream>>>(partial, nb);
    k_finalize<<<nb, SCAN_B, 0, stream>>>(cnt, partial, row_start, cursor, dinv, N, E);
    k_scatter<<<2048, 256, 0, stream>>>(ei, E, flag, cursor, esrc);

    const int gemm_grid = (N + BM - 1) / BM;
    const int agg_grid  = (N + 3) / 4;   // 4 waves per 256-thread block

    // layer 0
    k_gemm<<<gemm_grid, 256, 0, stream>>>(x, W0, dinv, hbuf, N);
    k_agg<<<agg_grid, 256, 0, stream>>>(hbuf, row_start, esrc, dinv, b0, out, N);
    // layer 1
    k_gemm<<<gemm_grid, 256, 0, stream>>>(out, W1, dinv, hbuf, N);
    k_agg<<<agg_grid, 256, 0, stream>>>(hbuf, row_start, esrc, dinv, b1, out, N);
    // layer 2
    k_gemm<<<gemm_grid, 256, 0, stream>>>(out, W2, dinv, hbuf, N);
    k_agg<<<agg_grid, 256, 0, stream>>>(hbuf, row_start, esrc, dinv, b2, out, N);
}

// Round 5
// 267.488 us; speedup vs baseline: 2.4623x; 1.4778x over previous
//
#include <hip/hip_runtime.h>
#include <hip/hip_fp16.h>

#define D 128
#define SCAN_B 256

typedef _Float16 f16x4 __attribute__((ext_vector_type(4)));
typedef float f32x4 __attribute__((ext_vector_type(4)));

// ---------------- dtype detection: int64 vs int32 edge_index ----------------
__global__ void k_detect64(const int* __restrict__ ei32, int* __restrict__ flag) {
    __shared__ int nz;
    if (threadIdx.x == 0) nz = 0;
    __syncthreads();
    int c = 0;
    for (int i = threadIdx.x; i < 1024; i += blockDim.x) {
        if (ei32[2 * i + 1] != 0) c++;   // int64 layout: high words all 0
    }
    atomicAdd(&nz, c);
    __syncthreads();
    if (threadIdx.x == 0) *flag = (nz == 0) ? 1 : 0;  // 1 => int64
}

__device__ __forceinline__ int e_src(const void* ei, int e, int is64, int E) {
    return is64 ? (int)((const long long*)ei)[e] : ((const int*)ei)[e];
}
__device__ __forceinline__ int e_dst(const void* ei, int e, int is64, int E) {
    return is64 ? (int)((const long long*)ei)[E + e] : ((const int*)ei)[E + e];
}

// ---------------- graph build ----------------
__global__ void k_hist(const void* __restrict__ ei, int E, const int* __restrict__ flag,
                       int* __restrict__ cnt) {
    int is64 = *flag;
    for (int e = blockIdx.x * blockDim.x + threadIdx.x; e < E; e += gridDim.x * blockDim.x) {
        atomicAdd(&cnt[e_dst(ei, e, is64, E)], 1);
    }
}

__global__ __launch_bounds__(SCAN_B) void k_block_sum(const int* __restrict__ cnt,
                                                      int* __restrict__ partial, int N) {
    __shared__ int sh[SCAN_B];
    int i = blockIdx.x * SCAN_B + threadIdx.x;
    sh[threadIdx.x] = (i < N) ? cnt[i] : 0;
    __syncthreads();
#pragma unroll
    for (int d = SCAN_B / 2; d > 0; d >>= 1) {
        if (threadIdx.x < d) sh[threadIdx.x] += sh[threadIdx.x + d];
        __syncthreads();
    }
    if (threadIdx.x == 0) partial[blockIdx.x] = sh[0];
}

__global__ __launch_bounds__(SCAN_B) void k_scan_partials(int* __restrict__ partial, int nb) {
    __shared__ int sh[SCAN_B];
    int v = (threadIdx.x < nb) ? partial[threadIdx.x] : 0;
    sh[threadIdx.x] = v;
    __syncthreads();
#pragma unroll
    for (int d = 1; d < SCAN_B; d <<= 1) {
        int t = (threadIdx.x >= d) ? sh[threadIdx.x - d] : 0;
        __syncthreads();
        sh[threadIdx.x] += t;
        __syncthreads();
    }
    if (threadIdx.x < nb) partial[threadIdx.x] = sh[threadIdx.x] - v;  // exclusive
}

__global__ __launch_bounds__(SCAN_B) void k_finalize(const int* __restrict__ cnt,
        const int* __restrict__ partial, int* __restrict__ row_start,
        int* __restrict__ cursor, float* __restrict__ dinv, int N, int E) {
    __shared__ int sh[SCAN_B];
    int i = blockIdx.x * SCAN_B + threadIdx.x;
    int v = (i < N) ? cnt[i] : 0;
    sh[threadIdx.x] = v;
    __syncthreads();
#pragma unroll
    for (int d = 1; d < SCAN_B; d <<= 1) {
        int t = (threadIdx.x >= d) ? sh[threadIdx.x - d] : 0;
        __syncthreads();
        sh[threadIdx.x] += t;
        __syncthreads();
    }
    if (i < N) {
        int excl = sh[threadIdx.x] - v + partial[blockIdx.x];
        row_start[i] = excl;
        cursor[i]    = excl;
        dinv[i]      = rsqrtf((float)(v + 1));
    }
    if (i == 0) row_start[N] = E;
}

__global__ void k_scatter(const void* __restrict__ ei, int E, const int* __restrict__ flag,
                          int* __restrict__ cursor, int* __restrict__ esrc) {
    int is64 = *flag;
    for (int e = blockIdx.x * blockDim.x + threadIdx.x; e < E; e += gridDim.x * blockDim.x) {
        int s = e_src(ei, e, is64, E);
        int d = e_dst(ei, e, is64, E);
        int pos = atomicAdd(&cursor[d], 1);
        esrc[pos] = s;
    }
}

// ---------------- W transpose+fp16 prep: Wt[c][k] = (half)W[k][c] ----------------
__global__ __launch_bounds__(256) void k_prep_w(const float* __restrict__ W,
                                                __half* __restrict__ Wt) {
    int tid = blockIdx.x * 256 + threadIdx.x;   // 4096 threads
    int c  = tid >> 5;
    int k4 = (tid & 31) * 4;
    float w0 = W[(k4 + 0) * D + c];
    float w1 = W[(k4 + 1) * D + c];
    float w2 = W[(k4 + 2) * D + c];
    float w3 = W[(k4 + 3) * D + c];
    union { __half2 h2[2]; uint2 u; } pk;
    pk.h2[0] = __floats2half2_rn(w0, w1);
    pk.h2[1] = __floats2half2_rn(w2, w3);
    *(uint2*)&Wt[(size_t)c * D + k4] = pk.u;
}

// ---------------- MFMA GEMM: h' = (x @ W) * dinv[row], fp16 out ----------------
// Block: 256 thr = 4 waves; tile M=128, N=128(all), K=128(all in LDS). One barrier.
// MFMA: v_mfma_f32_16x16x16f16 (known layout: A row=l&15, k=(l>>4)*4+e;
//       C col=l&15, row=(l>>4)*4+reg). LDS XOR-swizzle byte^=((row&7)<<4).
template<bool IN16>
__global__ __launch_bounds__(256) void k_gemm_mfma(const void* __restrict__ xin,
        const __half* __restrict__ Wt, const float* __restrict__ dinv,
        __half* __restrict__ h, int N) {
    __shared__ __align__(16) char Ab[128 * 256];   // 128 rows x 128 halves
    __shared__ __align__(16) char Bb[128 * 256];   // 128 cols x 128 halves (Wt)
    int t = threadIdx.x;
    int br = blockIdx.x * 128;

    // stage B: Wt [c][k] fp16, 32KB, swizzled copy
#pragma unroll
    for (int i = 0; i < 8; ++i) {
        int byte = (i * 256 + t) * 16;
        int c = byte >> 8;
        uint4 v = *(const uint4*)((const char*)Wt + byte);
        *(uint4*)(Bb + (byte ^ ((c & 7) << 4))) = v;
    }
    // stage A (rows of x), f32->fp16 or fp16 copy, swizzled
    if (IN16) {
        const char* xp = (const char*)xin;
#pragma unroll
        for (int i = 0; i < 8; ++i) {
            int byte = (i * 256 + t) * 16;
            int row = byte >> 8;
            int gr = br + row;
            uint4 v = make_uint4(0, 0, 0, 0);
            if (gr < N) v = *(const uint4*)(xp + (size_t)gr * 256 + (byte & 255));
            *(uint4*)(Ab + (byte ^ ((row & 7) << 4))) = v;
        }
    } else {
        const float* xp = (const float*)xin;
#pragma unroll
        for (int i = 0; i < 16; ++i) {
            int fid = i * 256 + t;
            int row = fid >> 5;
            int col4 = (fid & 31) * 4;
            int gr = br + row;
            float4 v = make_float4(0.f, 0.f, 0.f, 0.f);
            if (gr < N) v = *(const float4*)&xp[(size_t)gr * D + col4];
            union { __half2 h2[2]; uint2 u; } pk;
            pk.h2[0] = __floats2half2_rn(v.x, v.y);
            pk.h2[1] = __floats2half2_rn(v.z, v.w);
            int byte = row * 256 + col4 * 2;
            *(uint2*)(Ab + (byte ^ ((row & 7) << 4))) = pk.u;
        }
    }
    __syncthreads();

    int w = t >> 6;
    int l = t & 63;
    int lrow = l & 15;
    int g = l >> 4;
    f32x4 acc[2][8] = {};
    int arow0 = w * 32 + lrow;
    int arow1 = arow0 + 16;
#pragma unroll
    for (int ks = 0; ks < 8; ++ks) {
        int kb = ks * 32 + g * 8;   // byte offset of this lane's 4 k-halves
        f16x4 a0 = *(const f16x4*)(Ab + ((arow0 * 256 + kb) ^ ((arow0 & 7) << 4)));
        f16x4 a1 = *(const f16x4*)(Ab + ((arow1 * 256 + kb) ^ ((arow1 & 7) << 4)));
#pragma unroll
        for (int nj = 0; nj < 8; ++nj) {
            int bc = nj * 16 + lrow;
            f16x4 b = *(const f16x4*)(Bb + ((bc * 256 + kb) ^ ((bc & 7) << 4)));
            acc[0][nj] = __builtin_amdgcn_mfma_f32_16x16x16f16(a0, b, acc[0][nj], 0, 0, 0);
            acc[1][nj] = __builtin_amdgcn_mfma_f32_16x16x16f16(a1, b, acc[1][nj], 0, 0, 0);
        }
    }
    // epilogue: scale by dinv[row], store fp16
#pragma unroll
    for (int mi = 0; mi < 2; ++mi) {
        int rbase = br + w * 32 + mi * 16 + g * 4;
#pragma unroll
        for (int r = 0; r < 4; ++r) {
            int gr = rbase + r;
            if (gr < N) {
                float sc = dinv[gr];
#pragma unroll
                for (int nj = 0; nj < 8; ++nj) {
                    h[(size_t)gr * D + nj * 16 + lrow] = __float2half(acc[mi][nj][r] * sc);
                }
            }
        }
    }
}

// ------ aggregation: relu(dinv[i]*(sum h'[s] + h'[i]) + bias) -> f32 out or fp16 act ----
template<int WRITE_F32>
__global__ __launch_bounds__(256) void k_agg(const __half* __restrict__ h,
        const int* __restrict__ row_start, const int* __restrict__ esrc,
        const float* __restrict__ dinv, const float* __restrict__ bias,
        float* __restrict__ out, __half* __restrict__ act, int N) {
    int wid = (blockIdx.x * blockDim.x + threadIdx.x) >> 6;
    int lane = threadIdx.x & 63;
    if (wid >= N) return;
    int i = wid;
    float di = dinv[i];
    const __half2* hv = (const __half2*)h;
    int j0 = row_start[i], j1 = row_start[i + 1];

    float2 f = __half22float2(hv[(size_t)i * 64 + lane]);   // self-loop h'[i]
    float accx = f.x, accy = f.y;

    int j = j0;
    for (; j + 4 <= j1; j += 4) {
        int s0 = esrc[j], s1 = esrc[j + 1], s2 = esrc[j + 2], s3 = esrc[j + 3];
        float2 f0 = __half22float2(hv[(size_t)s0 * 64 + lane]);
        float2 f1 = __half22float2(hv[(size_t)s1 * 64 + lane]);
        float2 f2 = __half22float2(hv[(size_t)s2 * 64 + lane]);
        float2 f3 = __half22float2(hv[(size_t)s3 * 64 + lane]);
        accx += (f0.x + f1.x) + (f2.x + f3.x);
        accy += (f0.y + f1.y) + (f2.y + f3.y);
    }
    for (; j < j1; ++j) {
        int s = esrc[j];
        float2 fs = __half22float2(hv[(size_t)s * 64 + lane]);
        accx += fs.x;
        accy += fs.y;
    }
    float2 bv = ((const float2*)bias)[lane];
    float ox = fmaxf(fmaf(accx, di, bv.x), 0.f);
    float oy = fmaxf(fmaf(accy, di, bv.y), 0.f);
    if (WRITE_F32) {
        ((float2*)out)[(size_t)i * 64 + lane] = make_float2(ox, oy);
    } else {
        ((__half2*)act)[(size_t)i * 64 + lane] = __floats2half2_rn(ox, oy);
    }
}

// ---------------- host launch ----------------
extern "C" void kernel_launch(void* const* d_in, const int* in_sizes, int n_in,
                              void* d_out, int out_size, void* d_ws, size_t ws_size,
                              hipStream_t stream) {
    const float* x  = (const float*)d_in[0];
    const void*  ei = d_in[1];
    const float* W0 = (const float*)d_in[2];
    const float* b0 = (const float*)d_in[3];
    const float* W1 = (const float*)d_in[4];
    const float* b1 = (const float*)d_in[5];
    const float* W2 = (const float*)d_in[6];
    const float* b2 = (const float*)d_in[7];
    float* out = (float*)d_out;

    const int N = in_sizes[0] / D;       // 50000
    const int E = in_sizes[1] / 2;       // 800000

    char* ws = (char*)d_ws;
    size_t off = 0;
    auto alloc = [&](size_t bytes) {
        char* p = ws + off;
        off = (off + bytes + 255) & ~(size_t)255;
        return p;
    };
    int*    flag      = (int*)alloc(4);
    int*    cnt       = (int*)alloc((size_t)N * 4);
    int*    row_start = (int*)alloc((size_t)(N + 1) * 4);
    int*    cursor    = (int*)alloc((size_t)N * 4);
    float*  dinv      = (float*)alloc((size_t)N * 4);
    int*    partial   = (int*)alloc((size_t)SCAN_B * 4);
    int*    esrc      = (int*)alloc((size_t)E * 4);
    __half* hbuf      = (__half*)alloc((size_t)N * D * 2);
    __half* act       = (__half*)alloc((size_t)N * D * 2);
    __half* Wt        = (__half*)alloc((size_t)D * D * 2);
    (void)ws_size;

    const int nb = (N + SCAN_B - 1) / SCAN_B;

    // graph build
    k_detect64<<<1, 256, 0, stream>>>((const int*)ei, flag);
    hipMemsetAsync(cnt, 0, (size_t)N * 4, stream);
    k_hist<<<2048, 256, 0, stream>>>(ei, E, flag, cnt);
    k_block_sum<<<nb, SCAN_B, 0, stream>>>(cnt, partial, N);
    k_scan_partials<<<1, SCAN_B, 0, stream>>>(partial, nb);
    k_finalize<<<nb, SCAN_B, 0, stream>>>(cnt, partial, row_start, cursor, dinv, N, E);
    k_scatter<<<2048, 256, 0, stream>>>(ei, E, flag, cursor, esrc);

    const int gemm_grid = (N + 127) / 128;   // 391
    const int agg_grid  = (N + 3) / 4;

    // layer 0: x(f32) -> hbuf -> act(fp16)
    k_prep_w<<<16, 256, 0, stream>>>(W0, Wt);
    k_gemm_mfma<false><<<gemm_grid, 256, 0, stream>>>(x, Wt, dinv, hbuf, N);
    k_agg<0><<<agg_grid, 256, 0, stream>>>(hbuf, row_start, esrc, dinv, b0, out, act, N);
    // layer 1: act -> hbuf -> act
    k_prep_w<<<16, 256, 0, stream>>>(W1, Wt);
    k_gemm_mfma<true><<<gemm_grid, 256, 0, stream>>>(act, Wt, dinv, hbuf, N);
    k_agg<0><<<agg_grid, 256, 0, stream>>>(hbuf, row_start, esrc, dinv, b1, out, act, N);
    // layer 2: act -> hbuf -> out(f32)
    k_prep_w<<<16, 256, 0, stream>>>(W2, Wt);
    k_gemm_mfma<true><<<gemm_grid, 256, 0, stream>>>(act, Wt, dinv, hbuf, N);
    k_agg<1><<<agg_grid, 256, 0, stream>>>(hbuf, row_start, esrc, dinv, b2, out, act, N);
}

// Round 6
// 267.262 us; speedup vs baseline: 2.4644x; 1.0008x over previous
//
#include <hip/hip_runtime.h>
#include <hip/hip_fp16.h>

#define D 128
#define SCAN_B 256
#define BIN_CH 8192

typedef _Float16 f16x4 __attribute__((ext_vector_type(4)));
typedef float f32x4 __attribute__((ext_vector_type(4)));

// ---------------- dtype detection: int64 vs int32 edge_index ----------------
__global__ void k_detect64(const int* __restrict__ ei32, int* __restrict__ flag) {
    __shared__ int nz;
    if (threadIdx.x == 0) nz = 0;
    __syncthreads();
    int c = 0;
    for (int i = threadIdx.x; i < 1024; i += blockDim.x) {
        if (ei32[2 * i + 1] != 0) c++;   // int64 layout: high words all 0
    }
    atomicAdd(&nz, c);
    __syncthreads();
    if (threadIdx.x == 0) *flag = (nz == 0) ? 1 : 0;  // 1 => int64
}

__device__ __forceinline__ int e_src(const void* ei, int e, int is64, int E) {
    return is64 ? (int)((const long long*)ei)[e] : ((const int*)ei)[e];
}
__device__ __forceinline__ int e_dst(const void* ei, int e, int is64, int E) {
    return is64 ? (int)((const long long*)ei)[E + e] : ((const int*)ei)[E + e];
}

// ---------------- graph build ----------------
__global__ void k_hist(const void* __restrict__ ei, int E, const int* __restrict__ flag,
                       int* __restrict__ cnt) {
    int is64 = *flag;
    for (int e = blockIdx.x * blockDim.x + threadIdx.x; e < E; e += gridDim.x * blockDim.x) {
        atomicAdd(&cnt[e_dst(ei, e, is64, E)], 1);
    }
}

__global__ __launch_bounds__(SCAN_B) void k_block_sum(const int* __restrict__ cnt,
                                                      int* __restrict__ partial, int N) {
    __shared__ int sh[SCAN_B];
    int i = blockIdx.x * SCAN_B + threadIdx.x;
    sh[threadIdx.x] = (i < N) ? cnt[i] : 0;
    __syncthreads();
#pragma unroll
    for (int d = SCAN_B / 2; d > 0; d >>= 1) {
        if (threadIdx.x < d) sh[threadIdx.x] += sh[threadIdx.x + d];
        __syncthreads();
    }
    if (threadIdx.x == 0) partial[blockIdx.x] = sh[0];
}

__global__ __launch_bounds__(SCAN_B) void k_scan_partials(int* __restrict__ partial, int nb) {
    __shared__ int sh[SCAN_B];
    int v = (threadIdx.x < nb) ? partial[threadIdx.x] : 0;
    sh[threadIdx.x] = v;
    __syncthreads();
#pragma unroll
    for (int d = 1; d < SCAN_B; d <<= 1) {
        int t = (threadIdx.x >= d) ? sh[threadIdx.x - d] : 0;
        __syncthreads();
        sh[threadIdx.x] += t;
        __syncthreads();
    }
    if (threadIdx.x < nb) partial[threadIdx.x] = sh[threadIdx.x] - v;  // exclusive
}

__global__ __launch_bounds__(SCAN_B) void k_finalize(const int* __restrict__ cnt,
        const int* __restrict__ partial, int* __restrict__ row_start,
        int* __restrict__ cursor, float* __restrict__ dinv, int N, int E) {
    __shared__ int sh[SCAN_B];
    int i = blockIdx.x * SCAN_B + threadIdx.x;
    int v = (i < N) ? cnt[i] : 0;
    sh[threadIdx.x] = v;
    __syncthreads();
#pragma unroll
    for (int d = 1; d < SCAN_B; d <<= 1) {
        int t = (threadIdx.x >= d) ? sh[threadIdx.x - d] : 0;
        __syncthreads();
        sh[threadIdx.x] += t;
        __syncthreads();
    }
    if (i < N) {
        int excl = sh[threadIdx.x] - v + partial[blockIdx.x];
        row_start[i] = excl;
        cursor[i]    = excl;
        dinv[i]      = rsqrtf((float)(v + 1));
    }
    if (i == 0) row_start[N] = E;
}

// bucket b covers nodes [b<<8, (b+1)<<8); its ebuck/esrc segment starts at row_start[b<<8]
__global__ void k_bucket_init(const int* __restrict__ row_start, int* __restrict__ bcur, int N) {
    int t = threadIdx.x;   // 256 threads, 1 block
    bcur[t] = row_start[min(t << 8, N)];
}

// phase 1: bin edges into bucket-grouped array with contiguous per-(block,bucket) runs
__global__ __launch_bounds__(256) void k_binning(const void* __restrict__ ei, int E,
        const int* __restrict__ flag, int* __restrict__ bcur, int2* __restrict__ ebuck) {
    __shared__ int lcnt[256];
    __shared__ int lbase[256];
    int is64 = *flag;
    int t = threadIdx.x;
    int e0 = blockIdx.x * BIN_CH;
    int e1 = min(e0 + BIN_CH, E);
    lcnt[t] = 0;
    __syncthreads();
    for (int e = e0 + t; e < e1; e += 256) {
        int d = e_dst(ei, e, is64, E);
        atomicAdd(&lcnt[d >> 8], 1);
    }
    __syncthreads();
    int c = lcnt[t];
    if (c > 0) lbase[t] = atomicAdd(&bcur[t], c);
    __syncthreads();
    lcnt[t] = 0;
    __syncthreads();
    for (int e = e0 + t; e < e1; e += 256) {
        int s = e_src(ei, e, is64, E);
        int d = e_dst(ei, e, is64, E);
        int b = d >> 8;
        int idx = atomicAdd(&lcnt[b], 1);
        ebuck[lbase[b] + idx] = make_int2(s, d);
    }
}

// phase 2: per-bucket CSR scatter; writes confined to the bucket's exclusive segment
__global__ __launch_bounds__(256) void k_scatter2(const int2* __restrict__ ebuck,
        const int* __restrict__ row_start, int* __restrict__ cursor,
        int* __restrict__ esrc, int N) {
    int b = blockIdx.x;
    int t = threadIdx.x;
    int lo = row_start[min(b << 8, N)];
    int hi = row_start[min((b + 1) << 8, N)];
    for (int j = lo + t; j < hi; j += 256) {
        int2 ed = ebuck[j];
        int pos = atomicAdd(&cursor[ed.y], 1);
        esrc[pos] = ed.x;
    }
}

// ---------------- W transpose+fp16 prep: Wt[c][k] = (half)W[k][c] ----------------
__global__ __launch_bounds__(256) void k_prep_w(const float* __restrict__ W,
                                                __half* __restrict__ Wt) {
    int tid = blockIdx.x * 256 + threadIdx.x;   // 4096 threads
    int c  = tid >> 5;
    int k4 = (tid & 31) * 4;
    float w0 = W[(k4 + 0) * D + c];
    float w1 = W[(k4 + 1) * D + c];
    float w2 = W[(k4 + 2) * D + c];
    float w3 = W[(k4 + 3) * D + c];
    union { __half2 h2[2]; uint2 u; } pk;
    pk.h2[0] = __floats2half2_rn(w0, w1);
    pk.h2[1] = __floats2half2_rn(w2, w3);
    *(uint2*)&Wt[(size_t)c * D + k4] = pk.u;
}

// ---------------- MFMA GEMM: h' = (x @ W) * dinv[row], fp16 out ----------------
template<bool IN16>
__global__ __launch_bounds__(256) void k_gemm_mfma(const void* __restrict__ xin,
        const __half* __restrict__ Wt, const float* __restrict__ dinv,
        __half* __restrict__ h, int N) {
    __shared__ __align__(16) char Ab[128 * 256];   // 128 rows x 128 halves
    __shared__ __align__(16) char Bb[128 * 256];   // 128 cols x 128 halves (Wt)
    int t = threadIdx.x;
    int br = blockIdx.x * 128;

#pragma unroll
    for (int i = 0; i < 8; ++i) {
        int byte = (i * 256 + t) * 16;
        int c = byte >> 8;
        uint4 v = *(const uint4*)((const char*)Wt + byte);
        *(uint4*)(Bb + (byte ^ ((c & 7) << 4))) = v;
    }
    if (IN16) {
        const char* xp = (const char*)xin;
#pragma unroll
        for (int i = 0; i < 8; ++i) {
            int byte = (i * 256 + t) * 16;
            int row = byte >> 8;
            int gr = br + row;
            uint4 v = make_uint4(0, 0, 0, 0);
            if (gr < N) v = *(const uint4*)(xp + (size_t)gr * 256 + (byte & 255));
            *(uint4*)(Ab + (byte ^ ((row & 7) << 4))) = v;
        }
    } else {
        const float* xp = (const float*)xin;
#pragma unroll
        for (int i = 0; i < 16; ++i) {
            int fid = i * 256 + t;
            int row = fid >> 5;
            int col4 = (fid & 31) * 4;
            int gr = br + row;
            float4 v = make_float4(0.f, 0.f, 0.f, 0.f);
            if (gr < N) v = *(const float4*)&xp[(size_t)gr * D + col4];
            union { __half2 h2[2]; uint2 u; } pk;
            pk.h2[0] = __floats2half2_rn(v.x, v.y);
            pk.h2[1] = __floats2half2_rn(v.z, v.w);
            int byte = row * 256 + col4 * 2;
            *(uint2*)(Ab + (byte ^ ((row & 7) << 4))) = pk.u;
        }
    }
    __syncthreads();

    int w = t >> 6;
    int l = t & 63;
    int lrow = l & 15;
    int g = l >> 4;
    f32x4 acc[2][8] = {};
    int arow0 = w * 32 + lrow;
    int arow1 = arow0 + 16;
#pragma unroll
    for (int ks = 0; ks < 8; ++ks) {
        int kb = ks * 32 + g * 8;
        f16x4 a0 = *(const f16x4*)(Ab + ((arow0 * 256 + kb) ^ ((arow0 & 7) << 4)));
        f16x4 a1 = *(const f16x4*)(Ab + ((arow1 * 256 + kb) ^ ((arow1 & 7) << 4)));
#pragma unroll
        for (int nj = 0; nj < 8; ++nj) {
            int bc = nj * 16 + lrow;
            f16x4 b = *(const f16x4*)(Bb + ((bc * 256 + kb) ^ ((bc & 7) << 4)));
            acc[0][nj] = __builtin_amdgcn_mfma_f32_16x16x16f16(a0, b, acc[0][nj], 0, 0, 0);
            acc[1][nj] = __builtin_amdgcn_mfma_f32_16x16x16f16(a1, b, acc[1][nj], 0, 0, 0);
        }
    }
#pragma unroll
    for (int mi = 0; mi < 2; ++mi) {
        int rbase = br + w * 32 + mi * 16 + g * 4;
#pragma unroll
        for (int r = 0; r < 4; ++r) {
            int gr = rbase + r;
            if (gr < N) {
                float sc = dinv[gr];
#pragma unroll
                for (int nj = 0; nj < 8; ++nj) {
                    h[(size_t)gr * D + nj * 16 + lrow] = __float2half(acc[mi][nj][r] * sc);
                }
            }
        }
    }
}

// ------ aggregation: relu(dinv[i]*(sum h'[s] + h'[i]) + bias) -> f32 out or fp16 act ----
template<int WRITE_F32>
__global__ __launch_bounds__(256) void k_agg(const __half* __restrict__ h,
        const int* __restrict__ row_start, const int* __restrict__ esrc,
        const float* __restrict__ dinv, const float* __restrict__ bias,
        float* __restrict__ out, __half* __restrict__ act, int N) {
    int wid = (blockIdx.x * blockDim.x + threadIdx.x) >> 6;
    int lane = threadIdx.x & 63;
    if (wid >= N) return;
    int i = wid;
    float di = dinv[i];
    const __half2* hv = (const __half2*)h;
    int j0 = row_start[i], j1 = row_start[i + 1];

    float2 f = __half22float2(hv[(size_t)i * 64 + lane]);   // self-loop h'[i]
    float accx = f.x, accy = f.y;

    int j = j0;
    for (; j + 4 <= j1; j += 4) {
        int s0 = esrc[j], s1 = esrc[j + 1], s2 = esrc[j + 2], s3 = esrc[j + 3];
        float2 f0 = __half22float2(hv[(size_t)s0 * 64 + lane]);
        float2 f1 = __half22float2(hv[(size_t)s1 * 64 + lane]);
        float2 f2 = __half22float2(hv[(size_t)s2 * 64 + lane]);
        float2 f3 = __half22float2(hv[(size_t)s3 * 64 + lane]);
        accx += (f0.x + f1.x) + (f2.x + f3.x);
        accy += (f0.y + f1.y) + (f2.y + f3.y);
    }
    for (; j < j1; ++j) {
        int s = esrc[j];
        float2 fs = __half22float2(hv[(size_t)s * 64 + lane]);
        accx += fs.x;
        accy += fs.y;
    }
    float2 bv = ((const float2*)bias)[lane];
    float ox = fmaxf(fmaf(accx, di, bv.x), 0.f);
    float oy = fmaxf(fmaf(accy, di, bv.y), 0.f);
    if (WRITE_F32) {
        ((float2*)out)[(size_t)i * 64 + lane] = make_float2(ox, oy);
    } else {
        ((__half2*)act)[(size_t)i * 64 + lane] = __floats2half2_rn(ox, oy);
    }
}

// ---------------- host launch ----------------
extern "C" void kernel_launch(void* const* d_in, const int* in_sizes, int n_in,
                              void* d_out, int out_size, void* d_ws, size_t ws_size,
                              hipStream_t stream) {
    const float* x  = (const float*)d_in[0];
    const void*  ei = d_in[1];
    const float* W0 = (const float*)d_in[2];
    const float* b0 = (const float*)d_in[3];
    const float* W1 = (const float*)d_in[4];
    const float* b1 = (const float*)d_in[5];
    const float* W2 = (const float*)d_in[6];
    const float* b2 = (const float*)d_in[7];
    float* out = (float*)d_out;

    const int N = in_sizes[0] / D;       // 50000
    const int E = in_sizes[1] / 2;       // 800000

    char* ws = (char*)d_ws;
    size_t off = 0;
    auto alloc = [&](size_t bytes) {
        char* p = ws + off;
        off = (off + bytes + 255) & ~(size_t)255;
        return p;
    };
    int*    flag      = (int*)alloc(4);
    int*    cnt       = (int*)alloc((size_t)N * 4);
    int*    row_start = (int*)alloc((size_t)(N + 1) * 4);
    int*    cursor    = (int*)alloc((size_t)N * 4);
    float*  dinv      = (float*)alloc((size_t)N * 4);
    int*    partial   = (int*)alloc((size_t)SCAN_B * 4);
    int*    bcur      = (int*)alloc(256 * 4);
    int*    esrc      = (int*)alloc((size_t)E * 4);
    __half* hbuf      = (__half*)alloc((size_t)N * D * 2);
    __half* act       = (__half*)alloc((size_t)N * D * 2);
    __half* Wt        = (__half*)alloc((size_t)D * D * 2);
    // ebuck (E * 8B = 6.4 MB) aliases hbuf+act (25.6 MB): graph build completes
    // before the first GEMM writes hbuf, stream-ordered.
    int2*   ebuck     = (int2*)hbuf;
    (void)ws_size;

    const int nb = (N + SCAN_B - 1) / SCAN_B;
    const int nbuck = (N + 255) >> 8;        // 196

    // graph build
    k_detect64<<<1, 256, 0, stream>>>((const int*)ei, flag);
    hipMemsetAsync(cnt, 0, (size_t)N * 4, stream);
    k_hist<<<2048, 256, 0, stream>>>(ei, E, flag, cnt);
    k_block_sum<<<nb, SCAN_B, 0, stream>>>(cnt, partial, N);
    k_scan_partials<<<1, SCAN_B, 0, stream>>>(partial, nb);
    k_finalize<<<nb, SCAN_B, 0, stream>>>(cnt, partial, row_start, cursor, dinv, N, E);
    k_bucket_init<<<1, 256, 0, stream>>>(row_start, bcur, N);
    k_binning<<<(E + BIN_CH - 1) / BIN_CH, 256, 0, stream>>>(ei, E, flag, bcur, ebuck);
    k_scatter2<<<nbuck, 256, 0, stream>>>(ebuck, row_start, cursor, esrc, N);

    const int gemm_grid = (N + 127) / 128;   // 391
    const int agg_grid  = (N + 3) / 4;

    // layer 0: x(f32) -> hbuf -> act(fp16)
    k_prep_w<<<16, 256, 0, stream>>>(W0, Wt);
    k_gemm_mfma<false><<<gemm_grid, 256, 0, stream>>>(x, Wt, dinv, hbuf, N);
    k_agg<0><<<agg_grid, 256, 0, stream>>>(hbuf, row_start, esrc, dinv, b0, out, act, N);
    // layer 1: act -> hbuf -> act
    k_prep_w<<<16, 256, 0, stream>>>(W1, Wt);
    k_gemm_mfma<true><<<gemm_grid, 256, 0, stream>>>(act, Wt, dinv, hbuf, N);
    k_agg<0><<<agg_grid, 256, 0, stream>>>(hbuf, row_start, esrc, dinv, b1, out, act, N);
    // layer 2: act -> hbuf -> out(f32)
    k_prep_w<<<16, 256, 0, stream>>>(W2, Wt);
    k_gemm_mfma<true><<<gemm_grid, 256, 0, stream>>>(act, Wt, dinv, hbuf, N);
    k_agg<1><<<agg_grid, 256, 0, stream>>>(hbuf, row_start, esrc, dinv, b2, out, act, N);
}

// Round 7
// 245.734 us; speedup vs baseline: 2.6803x; 1.0876x over previous
//
#include <hip/hip_runtime.h>
#include <hip/hip_fp16.h>

#define D 128
#define SCAN_B 256
#define BIN_CH 8192

typedef _Float16 f16x4 __attribute__((ext_vector_type(4)));
typedef float f32x4 __attribute__((ext_vector_type(4)));

// ---------------- dtype detection: int64 vs int32 edge_index ----------------
__global__ void k_detect64(const int* __restrict__ ei32, int* __restrict__ flag) {
    __shared__ int nz;
    if (threadIdx.x == 0) nz = 0;
    __syncthreads();
    int c = 0;
    for (int i = threadIdx.x; i < 1024; i += blockDim.x) {
        if (ei32[2 * i + 1] != 0) c++;   // int64 layout: high words all 0
    }
    atomicAdd(&nz, c);
    __syncthreads();
    if (threadIdx.x == 0) *flag = (nz == 0) ? 1 : 0;  // 1 => int64
}

__device__ __forceinline__ int e_src(const void* ei, int e, int is64, int E) {
    return is64 ? (int)((const long long*)ei)[e] : ((const int*)ei)[e];
}
__device__ __forceinline__ int e_dst(const void* ei, int e, int is64, int E) {
    return is64 ? (int)((const long long*)ei)[E + e] : ((const int*)ei)[E + e];
}

// ---------------- graph build ----------------
__global__ void k_hist(const void* __restrict__ ei, int E, const int* __restrict__ flag,
                       int* __restrict__ cnt) {
    int is64 = *flag;
    for (int e = blockIdx.x * blockDim.x + threadIdx.x; e < E; e += gridDim.x * blockDim.x) {
        atomicAdd(&cnt[e_dst(ei, e, is64, E)], 1);
    }
}

__global__ __launch_bounds__(SCAN_B) void k_block_sum(const int* __restrict__ cnt,
                                                      int* __restrict__ partial, int N) {
    __shared__ int sh[SCAN_B];
    int i = blockIdx.x * SCAN_B + threadIdx.x;
    sh[threadIdx.x] = (i < N) ? cnt[i] : 0;
    __syncthreads();
#pragma unroll
    for (int d = SCAN_B / 2; d > 0; d >>= 1) {
        if (threadIdx.x < d) sh[threadIdx.x] += sh[threadIdx.x + d];
        __syncthreads();
    }
    if (threadIdx.x == 0) partial[blockIdx.x] = sh[0];
}

__global__ __launch_bounds__(SCAN_B) void k_scan_partials(int* __restrict__ partial, int nb) {
    __shared__ int sh[SCAN_B];
    int v = (threadIdx.x < nb) ? partial[threadIdx.x] : 0;
    sh[threadIdx.x] = v;
    __syncthreads();
#pragma unroll
    for (int d = 1; d < SCAN_B; d <<= 1) {
        int t = (threadIdx.x >= d) ? sh[threadIdx.x - d] : 0;
        __syncthreads();
        sh[threadIdx.x] += t;
        __syncthreads();
    }
    if (threadIdx.x < nb) partial[threadIdx.x] = sh[threadIdx.x] - v;  // exclusive
}

// also emits bcur[b] = row_start[b<<8] (bucket segment bases), replacing k_bucket_init
__global__ __launch_bounds__(SCAN_B) void k_finalize(const int* __restrict__ cnt,
        const int* __restrict__ partial, int* __restrict__ row_start,
        int* __restrict__ cursor, float* __restrict__ dinv, int* __restrict__ bcur,
        int N, int E) {
    __shared__ int sh[SCAN_B];
    int i = blockIdx.x * SCAN_B + threadIdx.x;
    int v = (i < N) ? cnt[i] : 0;
    sh[threadIdx.x] = v;
    __syncthreads();
#pragma unroll
    for (int d = 1; d < SCAN_B; d <<= 1) {
        int t = (threadIdx.x >= d) ? sh[threadIdx.x - d] : 0;
        __syncthreads();
        sh[threadIdx.x] += t;
        __syncthreads();
    }
    if (i < N) {
        int excl = sh[threadIdx.x] - v + partial[blockIdx.x];
        row_start[i] = excl;
        cursor[i]    = excl;
        dinv[i]      = rsqrtf((float)(v + 1));
        if ((i & 255) == 0) bcur[i >> 8] = excl;
    }
    if (i == 0) row_start[N] = E;
}

// phase 1: bin edges into bucket-grouped array with contiguous per-(block,bucket) runs
__global__ __launch_bounds__(256) void k_binning(const void* __restrict__ ei, int E,
        const int* __restrict__ flag, int* __restrict__ bcur, int2* __restrict__ ebuck) {
    __shared__ int lcnt[256];
    __shared__ int lbase[256];
    int is64 = *flag;
    int t = threadIdx.x;
    int e0 = blockIdx.x * BIN_CH;
    int e1 = min(e0 + BIN_CH, E);
    lcnt[t] = 0;
    __syncthreads();
    for (int e = e0 + t; e < e1; e += 256) {
        int d = e_dst(ei, e, is64, E);
        atomicAdd(&lcnt[d >> 8], 1);
    }
    __syncthreads();
    int c = lcnt[t];
    if (c > 0) lbase[t] = atomicAdd(&bcur[t], c);
    __syncthreads();
    lcnt[t] = 0;
    __syncthreads();
    for (int e = e0 + t; e < e1; e += 256) {
        int s = e_src(ei, e, is64, E);
        int d = e_dst(ei, e, is64, E);
        int b = d >> 8;
        int idx = atomicAdd(&lcnt[b], 1);
        ebuck[lbase[b] + idx] = make_int2(s, d);
    }
}

// phase 2: per-bucket CSR scatter; writes confined to the bucket's exclusive segment
__global__ __launch_bounds__(256) void k_scatter2(const int2* __restrict__ ebuck,
        const int* __restrict__ row_start, int* __restrict__ cursor,
        int* __restrict__ esrc, int N) {
    int b = blockIdx.x;
    int t = threadIdx.x;
    int lo = row_start[min(b << 8, N)];
    int hi = row_start[min((b + 1) << 8, N)];
    for (int j = lo + t; j < hi; j += 256) {
        int2 ed = ebuck[j];
        int pos = atomicAdd(&cursor[ed.y], 1);
        esrc[pos] = ed.x;
    }
}

// -------- W transpose+fp16 prep, all 3 layers: Wt[l][c][k] = (half)W_l[k][c] --------
__global__ __launch_bounds__(256) void k_prep_w3(const float* __restrict__ W0,
        const float* __restrict__ W1, const float* __restrict__ W2,
        __half* __restrict__ Wt) {
    int which = blockIdx.x >> 4;              // 16 blocks per weight
    const float* W = (which == 0) ? W0 : (which == 1) ? W1 : W2;
    __half* dst = Wt + (size_t)which * D * D;
    int tid = (blockIdx.x & 15) * 256 + threadIdx.x;   // 4096 per weight
    int c  = tid >> 5;
    int k4 = (tid & 31) * 4;
    float w0 = W[(k4 + 0) * D + c];
    float w1 = W[(k4 + 1) * D + c];
    float w2 = W[(k4 + 2) * D + c];
    float w3 = W[(k4 + 3) * D + c];
    union { __half2 h2[2]; uint2 u; } pk;
    pk.h2[0] = __floats2half2_rn(w0, w1);
    pk.h2[1] = __floats2half2_rn(w2, w3);
    *(uint2*)&dst[(size_t)c * D + k4] = pk.u;
}

// ---------------- MFMA GEMM: h' = (x @ W) * dinv[row], fp16 out ----------------
template<bool IN16>
__global__ __launch_bounds__(256) void k_gemm_mfma(const void* __restrict__ xin,
        const __half* __restrict__ Wt, const float* __restrict__ dinv,
        __half* __restrict__ h, int N) {
    __shared__ __align__(16) char Ab[128 * 256];   // 128 rows x 128 halves
    __shared__ __align__(16) char Bb[128 * 256];   // 128 cols x 128 halves (Wt)
    int t = threadIdx.x;
    int br = blockIdx.x * 128;

#pragma unroll
    for (int i = 0; i < 8; ++i) {
        int byte = (i * 256 + t) * 16;
        int c = byte >> 8;
        uint4 v = *(const uint4*)((const char*)Wt + byte);
        *(uint4*)(Bb + (byte ^ ((c & 7) << 4))) = v;
    }
    if (IN16) {
        const char* xp = (const char*)xin;
#pragma unroll
        for (int i = 0; i < 8; ++i) {
            int byte = (i * 256 + t) * 16;
            int row = byte >> 8;
            int gr = br + row;
            uint4 v = make_uint4(0, 0, 0, 0);
            if (gr < N) v = *(const uint4*)(xp + (size_t)gr * 256 + (byte & 255));
            *(uint4*)(Ab + (byte ^ ((row & 7) << 4))) = v;
        }
    } else {
        const float* xp = (const float*)xin;
#pragma unroll
        for (int i = 0; i < 16; ++i) {
            int fid = i * 256 + t;
            int row = fid >> 5;
            int col4 = (fid & 31) * 4;
            int gr = br + row;
            float4 v = make_float4(0.f, 0.f, 0.f, 0.f);
            if (gr < N) v = *(const float4*)&xp[(size_t)gr * D + col4];
            union { __half2 h2[2]; uint2 u; } pk;
            pk.h2[0] = __floats2half2_rn(v.x, v.y);
            pk.h2[1] = __floats2half2_rn(v.z, v.w);
            int byte = row * 256 + col4 * 2;
            *(uint2*)(Ab + (byte ^ ((row & 7) << 4))) = pk.u;
        }
    }
    __syncthreads();

    int w = t >> 6;
    int l = t & 63;
    int lrow = l & 15;
    int g = l >> 4;
    f32x4 acc[2][8] = {};
    int arow0 = w * 32 + lrow;
    int arow1 = arow0 + 16;
#pragma unroll
    for (int ks = 0; ks < 8; ++ks) {
        int kb = ks * 32 + g * 8;
        f16x4 a0 = *(const f16x4*)(Ab + ((arow0 * 256 + kb) ^ ((arow0 & 7) << 4)));
        f16x4 a1 = *(const f16x4*)(Ab + ((arow1 * 256 + kb) ^ ((arow1 & 7) << 4)));
#pragma unroll
        for (int nj = 0; nj < 8; ++nj) {
            int bc = nj * 16 + lrow;
            f16x4 b = *(const f16x4*)(Bb + ((bc * 256 + kb) ^ ((bc & 7) << 4)));
            acc[0][nj] = __builtin_amdgcn_mfma_f32_16x16x16f16(a0, b, acc[0][nj], 0, 0, 0);
            acc[1][nj] = __builtin_amdgcn_mfma_f32_16x16x16f16(a1, b, acc[1][nj], 0, 0, 0);
        }
    }
#pragma unroll
    for (int mi = 0; mi < 2; ++mi) {
        int rbase = br + w * 32 + mi * 16 + g * 4;
#pragma unroll
        for (int r = 0; r < 4; ++r) {
            int gr = rbase + r;
            if (gr < N) {
                float sc = dinv[gr];
#pragma unroll
                for (int nj = 0; nj < 8; ++nj) {
                    h[(size_t)gr * D + nj * 16 + lrow] = __float2half(acc[mi][nj][r] * sc);
                }
            }
        }
    }
}

// ------ aggregation: relu(dinv[i]*(sum h'[s] + h'[i]) + bias) -> f32 out or fp16 act ----
// One node per 32-lane half-wave: 2 nodes/wave x unroll-4 = 8 gathers in flight/wave.
template<int WRITE_F32>
__global__ __launch_bounds__(256) void k_agg(const __half* __restrict__ h,
        const int* __restrict__ row_start, const int* __restrict__ esrc,
        const float* __restrict__ dinv, const float* __restrict__ bias,
        float* __restrict__ out, __half* __restrict__ act, int N) {
    int node = (blockIdx.x * blockDim.x + threadIdx.x) >> 5;
    int l32 = threadIdx.x & 31;
    if (node >= N) return;
    float di = dinv[node];
    const uint2* hv = (const uint2*)h;   // 32 x uint2 (4 halves) per 128-col row
    int j0 = row_start[node], j1 = row_start[node + 1];

    // self-loop term h'[node]
    uint2 u = hv[(size_t)node * 32 + l32];
    float2 p0 = __half22float2(*(const __half2*)&u.x);
    float2 p1 = __half22float2(*(const __half2*)&u.y);
    float a0 = p0.x, a1 = p0.y, a2 = p1.x, a3 = p1.y;

    int j = j0;
    for (; j + 4 <= j1; j += 4) {
        int s0 = esrc[j], s1 = esrc[j + 1], s2 = esrc[j + 2], s3 = esrc[j + 3];
        uint2 u0 = hv[(size_t)s0 * 32 + l32];
        uint2 u1 = hv[(size_t)s1 * 32 + l32];
        uint2 u2 = hv[(size_t)s2 * 32 + l32];
        uint2 u3 = hv[(size_t)s3 * 32 + l32];
        float2 q;
        q = __half22float2(*(const __half2*)&u0.x); a0 += q.x; a1 += q.y;
        q = __half22float2(*(const __half2*)&u0.y); a2 += q.x; a3 += q.y;
        q = __half22float2(*(const __half2*)&u1.x); a0 += q.x; a1 += q.y;
        q = __half22float2(*(const __half2*)&u1.y); a2 += q.x; a3 += q.y;
        q = __half22float2(*(const __half2*)&u2.x); a0 += q.x; a1 += q.y;
        q = __half22float2(*(const __half2*)&u2.y); a2 += q.x; a3 += q.y;
        q = __half22float2(*(const __half2*)&u3.x); a0 += q.x; a1 += q.y;
        q = __half22float2(*(const __half2*)&u3.y); a2 += q.x; a3 += q.y;
    }
    for (; j < j1; ++j) {
        int s = esrc[j];
        uint2 us = hv[(size_t)s * 32 + l32];
        float2 q;
        q = __half22float2(*(const __half2*)&us.x); a0 += q.x; a1 += q.y;
        q = __half22float2(*(const __half2*)&us.y); a2 += q.x; a3 += q.y;
    }
    float4 bv = ((const float4*)bias)[l32];
    float o0 = fmaxf(fmaf(a0, di, bv.x), 0.f);
    float o1 = fmaxf(fmaf(a1, di, bv.y), 0.f);
    float o2 = fmaxf(fmaf(a2, di, bv.z), 0.f);
    float o3 = fmaxf(fmaf(a3, di, bv.w), 0.f);
    if (WRITE_F32) {
        ((float4*)out)[(size_t)node * 32 + l32] = make_float4(o0, o1, o2, o3);
    } else {
        union { __half2 h2[2]; uint2 u; } pk;
        pk.h2[0] = __floats2half2_rn(o0, o1);
        pk.h2[1] = __floats2half2_rn(o2, o3);
        ((uint2*)act)[(size_t)node * 32 + l32] = pk.u;
    }
}

// ---------------- host launch ----------------
extern "C" void kernel_launch(void* const* d_in, const int* in_sizes, int n_in,
                              void* d_out, int out_size, void* d_ws, size_t ws_size,
                              hipStream_t stream) {
    const float* x  = (const float*)d_in[0];
    const void*  ei = d_in[1];
    const float* W0 = (const float*)d_in[2];
    const float* b0 = (const float*)d_in[3];
    const float* W1 = (const float*)d_in[4];
    const float* b1 = (const float*)d_in[5];
    const float* W2 = (const float*)d_in[6];
    const float* b2 = (const float*)d_in[7];
    float* out = (float*)d_out;

    const int N = in_sizes[0] / D;       // 50000
    const int E = in_sizes[1] / 2;       // 800000

    char* ws = (char*)d_ws;
    size_t off = 0;
    auto alloc = [&](size_t bytes) {
        char* p = ws + off;
        off = (off + bytes + 255) & ~(size_t)255;
        return p;
    };
    int*    flag      = (int*)alloc(4);
    int*    cnt       = (int*)alloc((size_t)N * 4);
    int*    row_start = (int*)alloc((size_t)(N + 1) * 4);
    int*    cursor    = (int*)alloc((size_t)N * 4);
    float*  dinv      = (float*)alloc((size_t)N * 4);
    int*    partial   = (int*)alloc((size_t)SCAN_B * 4);
    int*    bcur      = (int*)alloc(256 * 4);
    int*    esrc      = (int*)alloc((size_t)E * 4);
    __half* hbuf      = (__half*)alloc((size_t)N * D * 2);
    __half* act       = (__half*)alloc((size_t)N * D * 2);
    __half* Wt        = (__half*)alloc((size_t)3 * D * D * 2);
    // ebuck (E*8B = 6.4 MB) aliases hbuf+act (25.6 MB): graph build completes
    // before the first GEMM writes hbuf, stream-ordered.
    int2*   ebuck     = (int2*)hbuf;
    (void)ws_size;

    const int nb = (N + SCAN_B - 1) / SCAN_B;
    const int nbuck = (N + 255) >> 8;        // 196

    // graph build + weight prep (prep has no deps on build)
    k_detect64<<<1, 256, 0, stream>>>((const int*)ei, flag);
    hipMemsetAsync(cnt, 0, (size_t)N * 4, stream);
    k_prep_w3<<<48, 256, 0, stream>>>(W0, W1, W2, Wt);
    k_hist<<<2048, 256, 0, stream>>>(ei, E, flag, cnt);
    k_block_sum<<<nb, SCAN_B, 0, stream>>>(cnt, partial, N);
    k_scan_partials<<<1, SCAN_B, 0, stream>>>(partial, nb);
    k_finalize<<<nb, SCAN_B, 0, stream>>>(cnt, partial, row_start, cursor, dinv, bcur, N, E);
    k_binning<<<(E + BIN_CH - 1) / BIN_CH, 256, 0, stream>>>(ei, E, flag, bcur, ebuck);
    k_scatter2<<<nbuck, 256, 0, stream>>>(ebuck, row_start, cursor, esrc, N);

    const int gemm_grid = (N + 127) / 128;   // 391
    const int agg_grid  = (N + 7) / 8;       // 8 nodes per 256-thread block

    // layer 0: x(f32) -> hbuf -> act(fp16)
    k_gemm_mfma<false><<<gemm_grid, 256, 0, stream>>>(x, Wt, dinv, hbuf, N);
    k_agg<0><<<agg_grid, 256, 0, stream>>>(hbuf, row_start, esrc, dinv, b0, out, act, N);
    // layer 1: act -> hbuf -> act
    k_gemm_mfma<true><<<gemm_grid, 256, 0, stream>>>(act, Wt + (size_t)D * D, dinv, hbuf, N);
    k_agg<0><<<agg_grid, 256, 0, stream>>>(hbuf, row_start, esrc, dinv, b1, out, act, N);
    // layer 2: act -> hbuf -> out(f32)
    k_gemm_mfma<true><<<gemm_grid, 256, 0, stream>>>(act, Wt + (size_t)2 * D * D, dinv, hbuf, N);
    k_agg<1><<<agg_grid, 256, 0, stream>>>(hbuf, row_start, esrc, dinv, b2, out, act, N);
}

// Round 8
// 197.520 us; speedup vs baseline: 3.3346x; 1.2441x over previous
//
#include <hip/hip_runtime.h>
#include <hip/hip_fp16.h>

#define D 128
#define BIN_CH 8192

typedef _Float16 f16x4 __attribute__((ext_vector_type(4)));
typedef float f32x4 __attribute__((ext_vector_type(4)));

// ------- dtype detection (int64 vs int32 edge_index) + bhist zero -------
__global__ void k_detect64(const int* __restrict__ ei32, int* __restrict__ flag,
                           int* __restrict__ bhist) {
    __shared__ int nz;
    if (threadIdx.x == 0) nz = 0;
    __syncthreads();
    int c = 0;
    for (int i = threadIdx.x; i < 1024; i += blockDim.x) {
        if (ei32[2 * i + 1] != 0) c++;   // int64 layout: high words all 0
    }
    atomicAdd(&nz, c);
    bhist[threadIdx.x] = 0;              // 256 entries zeroed
    __syncthreads();
    if (threadIdx.x == 0) *flag = (nz == 0) ? 1 : 0;  // 1 => int64
}

__device__ __forceinline__ int e_src(const void* ei, int e, int is64, int E) {
    return is64 ? (int)((const long long*)ei)[e] : ((const int*)ei)[e];
}
__device__ __forceinline__ int e_dst(const void* ei, int e, int is64, int E) {
    return is64 ? (int)((const long long*)ei)[E + e] : ((const int*)ei)[E + e];
}

// ---- bucket histogram: bhist[b] = #edges with dst in [b<<8,(b+1)<<8) ----
__global__ __launch_bounds__(256) void k_bucket_hist(const void* __restrict__ ei, int E,
        const int* __restrict__ flag, int* __restrict__ bhist) {
    __shared__ int lh[256];
    int is64 = *flag;
    int t = threadIdx.x;
    lh[t] = 0;
    __syncthreads();
    int e0 = blockIdx.x * BIN_CH;
    int e1 = min(e0 + BIN_CH, E);
    for (int e = e0 + t; e < e1; e += 256) {
        int d = e_dst(ei, e, is64, E);
        atomicAdd(&lh[d >> 8], 1);
    }
    __syncthreads();
    if (lh[t] > 0) atomicAdd(&bhist[t], lh[t]);
}

// ---- bucket scan: bbase = exclusive scan of bhist; bcur = copy ----
__global__ __launch_bounds__(256) void k_bucket_scan(const int* __restrict__ bhist,
        int* __restrict__ bbase, int* __restrict__ bcur, int nbuck, int E) {
    __shared__ int sh[256];
    int t = threadIdx.x;
    int v = (t < nbuck) ? bhist[t] : 0;
    sh[t] = v;
    __syncthreads();
#pragma unroll
    for (int d = 1; d < 256; d <<= 1) {
        int tv = (t >= d) ? sh[t - d] : 0;
        __syncthreads();
        sh[t] += tv;
        __syncthreads();
    }
    int excl = sh[t] - v;
    if (t < nbuck) { bbase[t] = excl; bcur[t] = excl; }
    if (t == 0) bbase[nbuck] = E;
}

// ---- binning: bucket-grouped (src,dst) array, contiguous per-(block,bucket) runs ----
__global__ __launch_bounds__(256) void k_binning(const void* __restrict__ ei, int E,
        const int* __restrict__ flag, int* __restrict__ bcur, int2* __restrict__ ebuck) {
    __shared__ int lcnt[256];
    __shared__ int lbase[256];
    int is64 = *flag;
    int t = threadIdx.x;
    int e0 = blockIdx.x * BIN_CH;
    int e1 = min(e0 + BIN_CH, E);
    lcnt[t] = 0;
    __syncthreads();
    for (int e = e0 + t; e < e1; e += 256) {
        int d = e_dst(ei, e, is64, E);
        atomicAdd(&lcnt[d >> 8], 1);
    }
    __syncthreads();
    int c = lcnt[t];
    if (c > 0) lbase[t] = atomicAdd(&bcur[t], c);
    __syncthreads();
    lcnt[t] = 0;
    __syncthreads();
    for (int e = e0 + t; e < e1; e += 256) {
        int s = e_src(ei, e, is64, E);
        int d = e_dst(ei, e, is64, E);
        int b = d >> 8;
        int idx = atomicAdd(&lcnt[b], 1);
        ebuck[lbase[b] + idx] = make_int2(s, d);
    }
}

// ---- bucket build: per-bucket degree count -> row_start/dinv + in-segment CSR scatter ----
__global__ __launch_bounds__(256) void k_bucket_build(const int2* __restrict__ ebuck,
        const int* __restrict__ bbase, int* __restrict__ row_start,
        float* __restrict__ dinv, int* __restrict__ esrc, int N, int E) {
    __shared__ int lcnt[256];
    __shared__ int sc[256];
    __shared__ int lbase2[256];
    int b = blockIdx.x;
    int t = threadIdx.x;
    int lo = bbase[b], hi = bbase[b + 1];
    lcnt[t] = 0;
    __syncthreads();
    for (int j = lo + t; j < hi; j += 256) {
        atomicAdd(&lcnt[ebuck[j].y & 255], 1);
    }
    __syncthreads();
    int cntv = lcnt[t];
    sc[t] = cntv;
    __syncthreads();
#pragma unroll
    for (int d = 1; d < 256; d <<= 1) {
        int tv = (t >= d) ? sc[t - d] : 0;
        __syncthreads();
        sc[t] += tv;
        __syncthreads();
    }
    lbase2[t] = lo + sc[t] - cntv;   // global CSR start for node (b<<8)+t
    int node = (b << 8) + t;
    if (node < N) {
        row_start[node] = lbase2[t];
        dinv[node] = rsqrtf((float)(cntv + 1));
    }
    if (b == gridDim.x - 1 && t == 0) row_start[N] = E;
    lcnt[t] = 0;
    __syncthreads();
    for (int j = lo + t; j < hi; j += 256) {
        int2 ed = ebuck[j];
        int c = ed.y & 255;
        int idx = atomicAdd(&lcnt[c], 1);
        esrc[lbase2[c] + idx] = ed.x;
    }
}

// -------- W transpose+fp16 prep, all 3 layers: Wt[l][c][k] = (half)W_l[k][c] --------
__global__ __launch_bounds__(256) void k_prep_w3(const float* __restrict__ W0,
        const float* __restrict__ W1, const float* __restrict__ W2,
        __half* __restrict__ Wt) {
    int which = blockIdx.x >> 4;              // 16 blocks per weight
    const float* W = (which == 0) ? W0 : (which == 1) ? W1 : W2;
    __half* dst = Wt + (size_t)which * D * D;
    int tid = (blockIdx.x & 15) * 256 + threadIdx.x;   // 4096 per weight
    int c  = tid >> 5;
    int k4 = (tid & 31) * 4;
    float w0 = W[(k4 + 0) * D + c];
    float w1 = W[(k4 + 1) * D + c];
    float w2 = W[(k4 + 2) * D + c];
    float w3 = W[(k4 + 3) * D + c];
    union { __half2 h2[2]; uint2 u; } pk;
    pk.h2[0] = __floats2half2_rn(w0, w1);
    pk.h2[1] = __floats2half2_rn(w2, w3);
    *(uint2*)&dst[(size_t)c * D + k4] = pk.u;
}

// ---------------- MFMA GEMM: h' = (x @ W) * dinv[row], fp16 out ----------------
template<bool IN16>
__global__ __launch_bounds__(256) void k_gemm_mfma(const void* __restrict__ xin,
        const __half* __restrict__ Wt, const float* __restrict__ dinv,
        __half* __restrict__ h, int N) {
    __shared__ __align__(16) char Ab[128 * 256];   // 128 rows x 128 halves
    __shared__ __align__(16) char Bb[128 * 256];   // 128 cols x 128 halves (Wt)
    int t = threadIdx.x;
    int br = blockIdx.x * 128;

#pragma unroll
    for (int i = 0; i < 8; ++i) {
        int byte = (i * 256 + t) * 16;
        int c = byte >> 8;
        uint4 v = *(const uint4*)((const char*)Wt + byte);
        *(uint4*)(Bb + (byte ^ ((c & 7) << 4))) = v;
    }
    if (IN16) {
        const char* xp = (const char*)xin;
#pragma unroll
        for (int i = 0; i < 8; ++i) {
            int byte = (i * 256 + t) * 16;
            int row = byte >> 8;
            int gr = br + row;
            uint4 v = make_uint4(0, 0, 0, 0);
            if (gr < N) v = *(const uint4*)(xp + (size_t)gr * 256 + (byte & 255));
            *(uint4*)(Ab + (byte ^ ((row & 7) << 4))) = v;
        }
    } else {
        const float* xp = (const float*)xin;
#pragma unroll
        for (int i = 0; i < 16; ++i) {
            int fid = i * 256 + t;
            int row = fid >> 5;
            int col4 = (fid & 31) * 4;
            int gr = br + row;
            float4 v = make_float4(0.f, 0.f, 0.f, 0.f);
            if (gr < N) v = *(const float4*)&xp[(size_t)gr * D + col4];
            union { __half2 h2[2]; uint2 u; } pk;
            pk.h2[0] = __floats2half2_rn(v.x, v.y);
            pk.h2[1] = __floats2half2_rn(v.z, v.w);
            int byte = row * 256 + col4 * 2;
            *(uint2*)(Ab + (byte ^ ((row & 7) << 4))) = pk.u;
        }
    }
    __syncthreads();

    int w = t >> 6;
    int l = t & 63;
    int lrow = l & 15;
    int g = l >> 4;
    f32x4 acc[2][8] = {};
    int arow0 = w * 32 + lrow;
    int arow1 = arow0 + 16;
#pragma unroll
    for (int ks = 0; ks < 8; ++ks) {
        int kb = ks * 32 + g * 8;
        f16x4 a0 = *(const f16x4*)(Ab + ((arow0 * 256 + kb) ^ ((arow0 & 7) << 4)));
        f16x4 a1 = *(const f16x4*)(Ab + ((arow1 * 256 + kb) ^ ((arow1 & 7) << 4)));
#pragma unroll
        for (int nj = 0; nj < 8; ++nj) {
            int bc = nj * 16 + lrow;
            f16x4 b = *(const f16x4*)(Bb + ((bc * 256 + kb) ^ ((bc & 7) << 4)));
            acc[0][nj] = __builtin_amdgcn_mfma_f32_16x16x16f16(a0, b, acc[0][nj], 0, 0, 0);
            acc[1][nj] = __builtin_amdgcn_mfma_f32_16x16x16f16(a1, b, acc[1][nj], 0, 0, 0);
        }
    }
#pragma unroll
    for (int mi = 0; mi < 2; ++mi) {
        int rbase = br + w * 32 + mi * 16 + g * 4;
#pragma unroll
        for (int r = 0; r < 4; ++r) {
            int gr = rbase + r;
            if (gr < N) {
                float sc = dinv[gr];
#pragma unroll
                for (int nj = 0; nj < 8; ++nj) {
                    h[(size_t)gr * D + nj * 16 + lrow] = __float2half(acc[mi][nj][r] * sc);
                }
            }
        }
    }
}

// ------ aggregation: relu(dinv[i]*(sum h'[s] + h'[i]) + bias) -> f32 out or fp16 act ----
// One node per 16 lanes (uint4/lane): 4 nodes/wave x unroll-4 = 16 gathers in flight.
__device__ __forceinline__ void acc_row(uint4 u, float* a) {
    float2 q;
    q = __half22float2(*(const __half2*)&u.x); a[0] += q.x; a[1] += q.y;
    q = __half22float2(*(const __half2*)&u.y); a[2] += q.x; a[3] += q.y;
    q = __half22float2(*(const __half2*)&u.z); a[4] += q.x; a[5] += q.y;
    q = __half22float2(*(const __half2*)&u.w); a[6] += q.x; a[7] += q.y;
}

template<int WRITE_F32>
__global__ __launch_bounds__(256) void k_agg(const __half* __restrict__ h,
        const int* __restrict__ row_start, const int* __restrict__ esrc,
        const float* __restrict__ dinv, const float* __restrict__ bias,
        float* __restrict__ out, __half* __restrict__ act, int N) {
    int node = (blockIdx.x * blockDim.x + threadIdx.x) >> 4;
    int l16 = threadIdx.x & 15;
    if (node >= N) return;
    float di = dinv[node];
    const uint4* hv = (const uint4*)h;   // 16 x uint4 (8 halves) per 128-col row
    int j0 = row_start[node], j1 = row_start[node + 1];

    float a[8] = {};
    acc_row(hv[(size_t)node * 16 + l16], a);   // self-loop h'[node]

    int j = j0;
    for (; j + 4 <= j1; j += 4) {
        int s0 = esrc[j], s1 = esrc[j + 1], s2 = esrc[j + 2], s3 = esrc[j + 3];
        uint4 u0 = hv[(size_t)s0 * 16 + l16];
        uint4 u1 = hv[(size_t)s1 * 16 + l16];
        uint4 u2 = hv[(size_t)s2 * 16 + l16];
        uint4 u3 = hv[(size_t)s3 * 16 + l16];
        acc_row(u0, a); acc_row(u1, a); acc_row(u2, a); acc_row(u3, a);
    }
    for (; j < j1; ++j) {
        acc_row(hv[(size_t)esrc[j] * 16 + l16], a);
    }
    const float4* b4 = (const float4*)bias;
    float4 bv0 = b4[l16 * 2], bv1 = b4[l16 * 2 + 1];
    float o[8];
    o[0] = fmaxf(fmaf(a[0], di, bv0.x), 0.f);
    o[1] = fmaxf(fmaf(a[1], di, bv0.y), 0.f);
    o[2] = fmaxf(fmaf(a[2], di, bv0.z), 0.f);
    o[3] = fmaxf(fmaf(a[3], di, bv0.w), 0.f);
    o[4] = fmaxf(fmaf(a[4], di, bv1.x), 0.f);
    o[5] = fmaxf(fmaf(a[5], di, bv1.y), 0.f);
    o[6] = fmaxf(fmaf(a[6], di, bv1.z), 0.f);
    o[7] = fmaxf(fmaf(a[7], di, bv1.w), 0.f);
    if (WRITE_F32) {
        float4* o4 = (float4*)out;
        o4[(size_t)node * 32 + l16 * 2]     = make_float4(o[0], o[1], o[2], o[3]);
        o4[(size_t)node * 32 + l16 * 2 + 1] = make_float4(o[4], o[5], o[6], o[7]);
    } else {
        union { __half2 h2[4]; uint4 u; } pk;
        pk.h2[0] = __floats2half2_rn(o[0], o[1]);
        pk.h2[1] = __floats2half2_rn(o[2], o[3]);
        pk.h2[2] = __floats2half2_rn(o[4], o[5]);
        pk.h2[3] = __floats2half2_rn(o[6], o[7]);
        ((uint4*)act)[(size_t)node * 16 + l16] = pk.u;
    }
}

// ---------------- host launch ----------------
extern "C" void kernel_launch(void* const* d_in, const int* in_sizes, int n_in,
                              void* d_out, int out_size, void* d_ws, size_t ws_size,
                              hipStream_t stream) {
    const float* x  = (const float*)d_in[0];
    const void*  ei = d_in[1];
    const float* W0 = (const float*)d_in[2];
    const float* b0 = (const float*)d_in[3];
    const float* W1 = (const float*)d_in[4];
    const float* b1 = (const float*)d_in[5];
    const float* W2 = (const float*)d_in[6];
    const float* b2 = (const float*)d_in[7];
    float* out = (float*)d_out;

    const int N = in_sizes[0] / D;       // 50000
    const int E = in_sizes[1] / 2;       // 800000

    char* ws = (char*)d_ws;
    size_t off = 0;
    auto alloc = [&](size_t bytes) {
        char* p = ws + off;
        off = (off + bytes + 255) & ~(size_t)255;
        return p;
    };
    int*    flag      = (int*)alloc(4);
    int*    bhist     = (int*)alloc(256 * 4);
    int*    bbase     = (int*)alloc(257 * 4);
    int*    bcur      = (int*)alloc(256 * 4);
    int*    row_start = (int*)alloc((size_t)(N + 1) * 4);
    float*  dinv      = (float*)alloc((size_t)N * 4);
    int*    esrc      = (int*)alloc((size_t)E * 4);
    __half* hbuf      = (__half*)alloc((size_t)N * D * 2);
    __half* act       = (__half*)alloc((size_t)N * D * 2);
    __half* Wt        = (__half*)alloc((size_t)3 * D * D * 2);
    // ebuck (E*8B = 6.4 MB) aliases hbuf+act (25.6 MB): graph build completes
    // before the first GEMM writes hbuf, stream-ordered.
    int2*   ebuck     = (int2*)hbuf;
    (void)ws_size;

    const int nbuck = (N + 255) >> 8;        // 196
    const int nbin  = (E + BIN_CH - 1) / BIN_CH;

    // graph build + weight prep
    k_detect64<<<1, 256, 0, stream>>>((const int*)ei, flag, bhist);
    k_prep_w3<<<48, 256, 0, stream>>>(W0, W1, W2, Wt);
    k_bucket_hist<<<nbin, 256, 0, stream>>>(ei, E, flag, bhist);
    k_bucket_scan<<<1, 256, 0, stream>>>(bhist, bbase, bcur, nbuck, E);
    k_binning<<<nbin, 256, 0, stream>>>(ei, E, flag, bcur, ebuck);
    k_bucket_build<<<nbuck, 256, 0, stream>>>(ebuck, bbase, row_start, dinv, esrc, N, E);

    const int gemm_grid = (N + 127) / 128;   // 391
    const int agg_grid  = (N + 15) / 16;     // 16 nodes per 256-thread block

    // layer 0: x(f32) -> hbuf -> act(fp16)
    k_gemm_mfma<false><<<gemm_grid, 256, 0, stream>>>(x, Wt, dinv, hbuf, N);
    k_agg<0><<<agg_grid, 256, 0, stream>>>(hbuf, row_start, esrc, dinv, b0, out, act, N);
    // layer 1: act -> hbuf -> act
    k_gemm_mfma<true><<<gemm_grid, 256, 0, stream>>>(act, Wt + (size_t)D * D, dinv, hbuf, N);
    k_agg<0><<<agg_grid, 256, 0, stream>>>(hbuf, row_start, esrc, dinv, b1, out, act, N);
    // layer 2: act -> hbuf -> out(f32)
    k_gemm_mfma<true><<<gemm_grid, 256, 0, stream>>>(act, Wt + (size_t)2 * D * D, dinv, hbuf, N);
    k_agg<1><<<agg_grid, 256, 0, stream>>>(hbuf, row_start, esrc, dinv, b2, out, act, N);
}

// Round 9
// 187.651 us; speedup vs baseline: 3.5099x; 1.0526x over previous
//
#include <hip/hip_runtime.h>
#include <hip/hip_fp16.h>

#define D 128
#define BIN_CH 8192
#define CAP 6144   // per-bucket edge capacity (mean 4081, sigma ~64 -> 32-sigma headroom)

typedef _Float16 f16x4 __attribute__((ext_vector_type(4)));
typedef float f32x4 __attribute__((ext_vector_type(4)));

// ---- k_init: block 0 = dtype-detect + bcur init; blocks 1..48 = W transpose->fp16 ----
__global__ __launch_bounds__(256) void k_init(const int* __restrict__ ei32,
        const float* __restrict__ W0, const float* __restrict__ W1,
        const float* __restrict__ W2, int* __restrict__ flag,
        int* __restrict__ bcur, __half* __restrict__ Wt) {
    if (blockIdx.x == 0) {
        __shared__ int nz;
        if (threadIdx.x == 0) nz = 0;
        __syncthreads();
        int c = 0;
        for (int i = threadIdx.x; i < 1024; i += blockDim.x) {
            if (ei32[2 * i + 1] != 0) c++;   // int64 layout: high words all 0
        }
        atomicAdd(&nz, c);
        bcur[threadIdx.x] = threadIdx.x * CAP;   // fixed bucket bases
        __syncthreads();
        if (threadIdx.x == 0) *flag = (nz == 0) ? 1 : 0;  // 1 => int64
        return;
    }
    int bb = blockIdx.x - 1;                  // 48 blocks: 16 per weight
    int which = bb >> 4;
    const float* W = (which == 0) ? W0 : (which == 1) ? W1 : W2;
    __half* dst = Wt + (size_t)which * D * D;
    int tid = (bb & 15) * 256 + threadIdx.x;  // 4096 per weight
    int c  = tid >> 5;
    int k4 = (tid & 31) * 4;
    float w0 = W[(k4 + 0) * D + c];
    float w1 = W[(k4 + 1) * D + c];
    float w2 = W[(k4 + 2) * D + c];
    float w3 = W[(k4 + 3) * D + c];
    union { __half2 h2[2]; uint2 u; } pk;
    pk.h2[0] = __floats2half2_rn(w0, w1);
    pk.h2[1] = __floats2half2_rn(w2, w3);
    *(uint2*)&dst[(size_t)c * D + k4] = pk.u;
}

__device__ __forceinline__ int e_src(const void* ei, int e, int is64, int E) {
    return is64 ? (int)((const long long*)ei)[e] : ((const int*)ei)[e];
}
__device__ __forceinline__ int e_dst(const void* ei, int e, int is64, int E) {
    return is64 ? (int)((const long long*)ei)[E + e] : ((const int*)ei)[E + e];
}

// ---- binning: bucket-grouped (src,dst) at fixed bases b*CAP, contiguous runs ----
__global__ __launch_bounds__(256) void k_binning(const void* __restrict__ ei, int E,
        const int* __restrict__ flag, int* __restrict__ bcur, int2* __restrict__ ebuck) {
    __shared__ int lcnt[256];
    __shared__ int lbase[256];
    int is64 = *flag;
    int t = threadIdx.x;
    int e0 = blockIdx.x * BIN_CH;
    int e1 = min(e0 + BIN_CH, E);
    lcnt[t] = 0;
    __syncthreads();
    for (int e = e0 + t; e < e1; e += 256) {
        int d = e_dst(ei, e, is64, E);
        atomicAdd(&lcnt[d >> 8], 1);
    }
    __syncthreads();
    int c = lcnt[t];
    if (c > 0) lbase[t] = atomicAdd(&bcur[t], c);
    __syncthreads();
    lcnt[t] = 0;
    __syncthreads();
    for (int e = e0 + t; e < e1; e += 256) {
        int s = e_src(ei, e, is64, E);
        int d = e_dst(ei, e, is64, E);
        int b = d >> 8;
        int idx = atomicAdd(&lcnt[b], 1);
        ebuck[lbase[b] + idx] = make_int2(s, d);
    }
}

// ---- bucket build: per-bucket degrees -> row_start/deg/dinv + in-segment CSR scatter ----
__global__ __launch_bounds__(256) void k_bucket_build(const int2* __restrict__ ebuck,
        const int* __restrict__ bcur, int* __restrict__ row_start,
        unsigned short* __restrict__ deg, float* __restrict__ dinv,
        int* __restrict__ esrc, int N) {
    __shared__ int lcnt[256];
    __shared__ int sc[256];
    __shared__ int lbase2[256];
    int b = blockIdx.x;
    int t = threadIdx.x;
    int lo = b * CAP;
    int hi = bcur[b];          // lo + count
    lcnt[t] = 0;
    __syncthreads();
    for (int j = lo + t; j < hi; j += 256) {
        atomicAdd(&lcnt[ebuck[j].y & 255], 1);
    }
    __syncthreads();
    int cntv = lcnt[t];
    sc[t] = cntv;
    __syncthreads();
#pragma unroll
    for (int d = 1; d < 256; d <<= 1) {
        int tv = (t >= d) ? sc[t - d] : 0;
        __syncthreads();
        sc[t] += tv;
        __syncthreads();
    }
    lbase2[t] = lo + sc[t] - cntv;   // CSR start for node (b<<8)+t (bucket-local base)
    int node = (b << 8) + t;
    if (node < N) {
        row_start[node] = lbase2[t];
        deg[node] = (unsigned short)cntv;
        dinv[node] = rsqrtf((float)(cntv + 1));
    }
    lcnt[t] = 0;
    __syncthreads();
    for (int j = lo + t; j < hi; j += 256) {
        int2 ed = ebuck[j];
        int c = ed.y & 255;
        int idx = atomicAdd(&lcnt[c], 1);
        esrc[lbase2[c] + idx] = ed.x;
    }
}

// ---------------- MFMA GEMM: h' = (x @ W) * dinv[row], fp16 out ----------------
template<bool IN16>
__global__ __launch_bounds__(256) void k_gemm_mfma(const void* __restrict__ xin,
        const __half* __restrict__ Wt, const float* __restrict__ dinv,
        __half* __restrict__ h, int N) {
    __shared__ __align__(16) char Ab[128 * 256];   // 128 rows x 128 halves
    __shared__ __align__(16) char Bb[128 * 256];   // 128 cols x 128 halves (Wt)
    int t = threadIdx.x;
    int br = blockIdx.x * 128;

#pragma unroll
    for (int i = 0; i < 8; ++i) {
        int byte = (i * 256 + t) * 16;
        int c = byte >> 8;
        uint4 v = *(const uint4*)((const char*)Wt + byte);
        *(uint4*)(Bb + (byte ^ ((c & 7) << 4))) = v;
    }
    if (IN16) {
        const char* xp = (const char*)xin;
#pragma unroll
        for (int i = 0; i < 8; ++i) {
            int byte = (i * 256 + t) * 16;
            int row = byte >> 8;
            int gr = br + row;
            uint4 v = make_uint4(0, 0, 0, 0);
            if (gr < N) v = *(const uint4*)(xp + (size_t)gr * 256 + (byte & 255));
            *(uint4*)(Ab + (byte ^ ((row & 7) << 4))) = v;
        }
    } else {
        const float* xp = (const float*)xin;
#pragma unroll
        for (int i = 0; i < 16; ++i) {
            int fid = i * 256 + t;
            int row = fid >> 5;
            int col4 = (fid & 31) * 4;
            int gr = br + row;
            float4 v = make_float4(0.f, 0.f, 0.f, 0.f);
            if (gr < N) v = *(const float4*)&xp[(size_t)gr * D + col4];
            union { __half2 h2[2]; uint2 u; } pk;
            pk.h2[0] = __floats2half2_rn(v.x, v.y);
            pk.h2[1] = __floats2half2_rn(v.z, v.w);
            int byte = row * 256 + col4 * 2;
            *(uint2*)(Ab + (byte ^ ((row & 7) << 4))) = pk.u;
        }
    }
    __syncthreads();

    int w = t >> 6;
    int l = t & 63;
    int lrow = l & 15;
    int g = l >> 4;
    f32x4 acc[2][8] = {};
    int arow0 = w * 32 + lrow;
    int arow1 = arow0 + 16;
#pragma unroll
    for (int ks = 0; ks < 8; ++ks) {
        int kb = ks * 32 + g * 8;
        f16x4 a0 = *(const f16x4*)(Ab + ((arow0 * 256 + kb) ^ ((arow0 & 7) << 4)));
        f16x4 a1 = *(const f16x4*)(Ab + ((arow1 * 256 + kb) ^ ((arow1 & 7) << 4)));
#pragma unroll
        for (int nj = 0; nj < 8; ++nj) {
            int bc = nj * 16 + lrow;
            f16x4 b = *(const f16x4*)(Bb + ((bc * 256 + kb) ^ ((bc & 7) << 4)));
            acc[0][nj] = __builtin_amdgcn_mfma_f32_16x16x16f16(a0, b, acc[0][nj], 0, 0, 0);
            acc[1][nj] = __builtin_amdgcn_mfma_f32_16x16x16f16(a1, b, acc[1][nj], 0, 0, 0);
        }
    }
#pragma unroll
    for (int mi = 0; mi < 2; ++mi) {
        int rbase = br + w * 32 + mi * 16 + g * 4;
#pragma unroll
        for (int r = 0; r < 4; ++r) {
            int gr = rbase + r;
            if (gr < N) {
                float sc = dinv[gr];
#pragma unroll
                for (int nj = 0; nj < 8; ++nj) {
                    h[(size_t)gr * D + nj * 16 + lrow] = __float2half(acc[mi][nj][r] * sc);
                }
            }
        }
    }
}

// ------ aggregation: relu(dinv[i]*(sum h'[s] + h'[i]) + bias) -> f32 out or fp16 act ----
// One node per 16 lanes (uint4/lane): 4 nodes/wave x unroll-8 = 32 gathers in flight.
__device__ __forceinline__ void acc_row(uint4 u, float* a) {
    float2 q;
    q = __half22float2(*(const __half2*)&u.x); a[0] += q.x; a[1] += q.y;
    q = __half22float2(*(const __half2*)&u.y); a[2] += q.x; a[3] += q.y;
    q = __half22float2(*(const __half2*)&u.z); a[4] += q.x; a[5] += q.y;
    q = __half22float2(*(const __half2*)&u.w); a[6] += q.x; a[7] += q.y;
}

template<int WRITE_F32>
__global__ __launch_bounds__(256) void k_agg(const __half* __restrict__ h,
        const int* __restrict__ row_start, const unsigned short* __restrict__ deg,
        const int* __restrict__ esrc, const float* __restrict__ dinv,
        const float* __restrict__ bias, float* __restrict__ out,
        __half* __restrict__ act, int N) {
    int node = (blockIdx.x * blockDim.x + threadIdx.x) >> 4;
    int l16 = threadIdx.x & 15;
    if (node >= N) return;
    float di = dinv[node];
    const uint4* hv = (const uint4*)h;   // 16 x uint4 (8 halves) per 128-col row
    int j0 = row_start[node];
    int j1 = j0 + deg[node];

    float a[8] = {};
    acc_row(hv[(size_t)node * 16 + l16], a);   // self-loop h'[node]

    int j = j0;
    for (; j + 8 <= j1; j += 8) {
        int s0 = esrc[j],     s1 = esrc[j + 1], s2 = esrc[j + 2], s3 = esrc[j + 3];
        int s4 = esrc[j + 4], s5 = esrc[j + 5], s6 = esrc[j + 6], s7 = esrc[j + 7];
        uint4 u0 = hv[(size_t)s0 * 16 + l16];
        uint4 u1 = hv[(size_t)s1 * 16 + l16];
        uint4 u2 = hv[(size_t)s2 * 16 + l16];
        uint4 u3 = hv[(size_t)s3 * 16 + l16];
        uint4 u4 = hv[(size_t)s4 * 16 + l16];
        uint4 u5 = hv[(size_t)s5 * 16 + l16];
        uint4 u6 = hv[(size_t)s6 * 16 + l16];
        uint4 u7 = hv[(size_t)s7 * 16 + l16];
        acc_row(u0, a); acc_row(u1, a); acc_row(u2, a); acc_row(u3, a);
        acc_row(u4, a); acc_row(u5, a); acc_row(u6, a); acc_row(u7, a);
    }
    for (; j + 4 <= j1; j += 4) {
        int s0 = esrc[j], s1 = esrc[j + 1], s2 = esrc[j + 2], s3 = esrc[j + 3];
        uint4 u0 = hv[(size_t)s0 * 16 + l16];
        uint4 u1 = hv[(size_t)s1 * 16 + l16];
        uint4 u2 = hv[(size_t)s2 * 16 + l16];
        uint4 u3 = hv[(size_t)s3 * 16 + l16];
        acc_row(u0, a); acc_row(u1, a); acc_row(u2, a); acc_row(u3, a);
    }
    for (; j < j1; ++j) {
        acc_row(hv[(size_t)esrc[j] * 16 + l16], a);
    }
    const float4* b4 = (const float4*)bias;
    float4 bv0 = b4[l16 * 2], bv1 = b4[l16 * 2 + 1];
    float o[8];
    o[0] = fmaxf(fmaf(a[0], di, bv0.x), 0.f);
    o[1] = fmaxf(fmaf(a[1], di, bv0.y), 0.f);
    o[2] = fmaxf(fmaf(a[2], di, bv0.z), 0.f);
    o[3] = fmaxf(fmaf(a[3], di, bv0.w), 0.f);
    o[4] = fmaxf(fmaf(a[4], di, bv1.x), 0.f);
    o[5] = fmaxf(fmaf(a[5], di, bv1.y), 0.f);
    o[6] = fmaxf(fmaf(a[6], di, bv1.z), 0.f);
    o[7] = fmaxf(fmaf(a[7], di, bv1.w), 0.f);
    if (WRITE_F32) {
        float4* o4 = (float4*)out;
        o4[(size_t)node * 32 + l16 * 2]     = make_float4(o[0], o[1], o[2], o[3]);
        o4[(size_t)node * 32 + l16 * 2 + 1] = make_float4(o[4], o[5], o[6], o[7]);
    } else {
        union { __half2 h2[4]; uint4 u; } pk;
        pk.h2[0] = __floats2half2_rn(o[0], o[1]);
        pk.h2[1] = __floats2half2_rn(o[2], o[3]);
        pk.h2[2] = __floats2half2_rn(o[4], o[5]);
        pk.h2[3] = __floats2half2_rn(o[6], o[7]);
        ((uint4*)act)[(size_t)node * 16 + l16] = pk.u;
    }
}

// ---------------- host launch ----------------
extern "C" void kernel_launch(void* const* d_in, const int* in_sizes, int n_in,
                              void* d_out, int out_size, void* d_ws, size_t ws_size,
                              hipStream_t stream) {
    const float* x  = (const float*)d_in[0];
    const void*  ei = d_in[1];
    const float* W0 = (const float*)d_in[2];
    const float* b0 = (const float*)d_in[3];
    const float* W1 = (const float*)d_in[4];
    const float* b1 = (const float*)d_in[5];
    const float* W2 = (const float*)d_in[6];
    const float* b2 = (const float*)d_in[7];
    float* out = (float*)d_out;

    const int N = in_sizes[0] / D;       // 50000
    const int E = in_sizes[1] / 2;       // 800000

    char* ws = (char*)d_ws;
    size_t off = 0;
    auto alloc = [&](size_t bytes) {
        char* p = ws + off;
        off = (off + bytes + 255) & ~(size_t)255;
        return p;
    };
    int*            flag      = (int*)alloc(4);
    int*            bcur      = (int*)alloc(256 * 4);
    int*            row_start = (int*)alloc((size_t)N * 4);
    unsigned short* deg       = (unsigned short*)alloc((size_t)N * 2);
    float*          dinv      = (float*)alloc((size_t)N * 4);
    int*            esrc      = (int*)alloc((size_t)256 * CAP * 4);
    __half*         hbuf      = (__half*)alloc((size_t)N * D * 2);
    __half*         act       = (__half*)alloc((size_t)N * D * 2);
    __half*         Wt        = (__half*)alloc((size_t)3 * D * D * 2);
    // ebuck (196*CAP*8B = 9.6MB) aliases hbuf (12.8MB): graph build completes
    // before the first GEMM writes hbuf, stream-ordered.
    int2*           ebuck     = (int2*)hbuf;
    (void)ws_size;

    const int nbuck = (N + 255) >> 8;        // 196
    const int nbin  = (E + BIN_CH - 1) / BIN_CH;

    // init (detect + bcur bases + W prep) -> binning -> bucket build
    k_init<<<49, 256, 0, stream>>>((const int*)ei, W0, W1, W2, flag, bcur, Wt);
    k_binning<<<nbin, 256, 0, stream>>>(ei, E, flag, bcur, ebuck);
    k_bucket_build<<<nbuck, 256, 0, stream>>>(ebuck, bcur, row_start, deg, dinv, esrc, N);

    const int gemm_grid = (N + 127) / 128;   // 391
    const int agg_grid  = (N + 15) / 16;     // 16 nodes per 256-thread block

    // layer 0: x(f32) -> hbuf -> act(fp16)
    k_gemm_mfma<false><<<gemm_grid, 256, 0, stream>>>(x, Wt, dinv, hbuf, N);
    k_agg<0><<<agg_grid, 256, 0, stream>>>(hbuf, row_start, deg, esrc, dinv, b0, out, act, N);
    // layer 1: act -> hbuf -> act
    k_gemm_mfma<true><<<gemm_grid, 256, 0, stream>>>(act, Wt + (size_t)D * D, dinv, hbuf, N);
    k_agg<0><<<agg_grid, 256, 0, stream>>>(hbuf, row_start, deg, esrc, dinv, b1, out, act, N);
    // layer 2: act -> hbuf -> out(f32)
    k_gemm_mfma<true><<<gemm_grid, 256, 0, stream>>>(act, Wt + (size_t)2 * D * D, dinv, hbuf, N);
    k_agg<1><<<agg_grid, 256, 0, stream>>>(hbuf, row_start, deg, esrc, dinv, b2, out, act, N);
}

// Round 10
// 176.542 us; speedup vs baseline: 3.7308x; 1.0629x over previous
//
#include <hip/hip_runtime.h>
#include <hip/hip_fp16.h>

#define D 128
#define BIN_CH 8192
#define CAP 6144   // per-bucket edge capacity (mean 4081, sigma ~64 -> 32-sigma headroom)

typedef _Float16 f16x4 __attribute__((ext_vector_type(4)));
typedef float f32x4 __attribute__((ext_vector_type(4)));

// ---- k_init: block 0 = dtype-detect + bcur init; blocks 1..48 = W transpose->fp16 ----
__global__ __launch_bounds__(256) void k_init(const int* __restrict__ ei32,
        const float* __restrict__ W0, const float* __restrict__ W1,
        const float* __restrict__ W2, int* __restrict__ flag,
        int* __restrict__ bcur, __half* __restrict__ Wt) {
    if (blockIdx.x == 0) {
        __shared__ int nz;
        if (threadIdx.x == 0) nz = 0;
        __syncthreads();
        int c = 0;
        for (int i = threadIdx.x; i < 1024; i += blockDim.x) {
            if (ei32[2 * i + 1] != 0) c++;   // int64 layout: high words all 0
        }
        atomicAdd(&nz, c);
        bcur[threadIdx.x] = threadIdx.x * CAP;   // fixed bucket bases
        __syncthreads();
        if (threadIdx.x == 0) *flag = (nz == 0) ? 1 : 0;  // 1 => int64
        return;
    }
    int bb = blockIdx.x - 1;                  // 48 blocks: 16 per weight
    int which = bb >> 4;
    const float* W = (which == 0) ? W0 : (which == 1) ? W1 : W2;
    __half* dst = Wt + (size_t)which * D * D;
    int tid = (bb & 15) * 256 + threadIdx.x;  // 4096 per weight
    int c  = tid >> 5;
    int k4 = (tid & 31) * 4;
    float w0 = W[(k4 + 0) * D + c];
    float w1 = W[(k4 + 1) * D + c];
    float w2 = W[(k4 + 2) * D + c];
    float w3 = W[(k4 + 3) * D + c];
    union { __half2 h2[2]; uint2 u; } pk;
    pk.h2[0] = __floats2half2_rn(w0, w1);
    pk.h2[1] = __floats2half2_rn(w2, w3);
    *(uint2*)&dst[(size_t)c * D + k4] = pk.u;
}

__device__ __forceinline__ int e_src(const void* ei, int e, int is64, int E) {
    return is64 ? (int)((const long long*)ei)[e] : ((const int*)ei)[e];
}
__device__ __forceinline__ int e_dst(const void* ei, int e, int is64, int E) {
    return is64 ? (int)((const long long*)ei)[E + e] : ((const int*)ei)[E + e];
}

// ---- binning: bucket-grouped (src,dst) at fixed bases b*CAP, contiguous runs ----
__global__ __launch_bounds__(256) void k_binning(const void* __restrict__ ei, int E,
        const int* __restrict__ flag, int* __restrict__ bcur, int2* __restrict__ ebuck) {
    __shared__ int lcnt[256];
    __shared__ int lbase[256];
    int is64 = *flag;
    int t = threadIdx.x;
    int e0 = blockIdx.x * BIN_CH;
    int e1 = min(e0 + BIN_CH, E);
    lcnt[t] = 0;
    __syncthreads();
    for (int e = e0 + t; e < e1; e += 256) {
        int d = e_dst(ei, e, is64, E);
        atomicAdd(&lcnt[d >> 8], 1);
    }
    __syncthreads();
    int c = lcnt[t];
    if (c > 0) lbase[t] = atomicAdd(&bcur[t], c);
    __syncthreads();
    lcnt[t] = 0;
    __syncthreads();
    for (int e = e0 + t; e < e1; e += 256) {
        int s = e_src(ei, e, is64, E);
        int d = e_dst(ei, e, is64, E);
        int b = d >> 8;
        int idx = atomicAdd(&lcnt[b], 1);
        ebuck[lbase[b] + idx] = make_int2(s, d);
    }
}

// ---- bucket build: per-bucket degrees -> row_start/deg/dinv + in-segment CSR scatter ----
__global__ __launch_bounds__(256) void k_bucket_build(const int2* __restrict__ ebuck,
        const int* __restrict__ bcur, int* __restrict__ row_start,
        unsigned short* __restrict__ deg, float* __restrict__ dinv,
        int* __restrict__ esrc, int N) {
    __shared__ int lcnt[256];
    __shared__ int sc[256];
    __shared__ int lbase2[256];
    int b = blockIdx.x;
    int t = threadIdx.x;
    int lo = b * CAP;
    int hi = bcur[b];          // lo + count
    lcnt[t] = 0;
    __syncthreads();
    for (int j = lo + t; j < hi; j += 256) {
        atomicAdd(&lcnt[ebuck[j].y & 255], 1);
    }
    __syncthreads();
    int cntv = lcnt[t];
    sc[t] = cntv;
    __syncthreads();
#pragma unroll
    for (int d = 1; d < 256; d <<= 1) {
        int tv = (t >= d) ? sc[t - d] : 0;
        __syncthreads();
        sc[t] += tv;
        __syncthreads();
    }
    lbase2[t] = lo + sc[t] - cntv;   // CSR start for node (b<<8)+t (bucket-local base)
    int node = (b << 8) + t;
    if (node < N) {
        row_start[node] = lbase2[t];
        deg[node] = (unsigned short)cntv;
        dinv[node] = rsqrtf((float)(cntv + 1));
    }
    lcnt[t] = 0;
    __syncthreads();
    for (int j = lo + t; j < hi; j += 256) {
        int2 ed = ebuck[j];
        int c = ed.y & 255;
        int idx = atomicAdd(&lcnt[c], 1);
        esrc[lbase2[c] + idx] = ed.x;
    }
}

// --------- MFMA GEMM: h' = (x @ W) * dinv[row], fp16 out, CHUNKED [4][N][32] ---------
template<bool IN16>
__global__ __launch_bounds__(256) void k_gemm_mfma(const void* __restrict__ xin,
        const __half* __restrict__ Wt, const float* __restrict__ dinv,
        __half* __restrict__ h, int N) {
    __shared__ __align__(16) char Ab[128 * 256];   // 128 rows x 128 halves
    __shared__ __align__(16) char Bb[128 * 256];   // 128 cols x 128 halves (Wt)
    int t = threadIdx.x;
    int br = blockIdx.x * 128;

#pragma unroll
    for (int i = 0; i < 8; ++i) {
        int byte = (i * 256 + t) * 16;
        int c = byte >> 8;
        uint4 v = *(const uint4*)((const char*)Wt + byte);
        *(uint4*)(Bb + (byte ^ ((c & 7) << 4))) = v;
    }
    if (IN16) {
        // input is chunked fp16 [4][N][32]
        const char* xp = (const char*)xin;
#pragma unroll
        for (int i = 0; i < 8; ++i) {
            int byte = (i * 256 + t) * 16;
            int row = byte >> 8;
            int gr = br + row;
            int co = byte & 255;           // byte offset within the 256B logical row
            uint4 v = make_uint4(0, 0, 0, 0);
            if (gr < N) {
                int chunk = co >> 6;       // 64 bytes (32 halves) per chunk
                v = *(const uint4*)(xp + (size_t)chunk * N * 64 + (size_t)gr * 64 + (co & 63));
            }
            *(uint4*)(Ab + (byte ^ ((row & 7) << 4))) = v;
        }
    } else {
        const float* xp = (const float*)xin;
#pragma unroll
        for (int i = 0; i < 16; ++i) {
            int fid = i * 256 + t;
            int row = fid >> 5;
            int col4 = (fid & 31) * 4;
            int gr = br + row;
            float4 v = make_float4(0.f, 0.f, 0.f, 0.f);
            if (gr < N) v = *(const float4*)&xp[(size_t)gr * D + col4];
            union { __half2 h2[2]; uint2 u; } pk;
            pk.h2[0] = __floats2half2_rn(v.x, v.y);
            pk.h2[1] = __floats2half2_rn(v.z, v.w);
            int byte = row * 256 + col4 * 2;
            *(uint2*)(Ab + (byte ^ ((row & 7) << 4))) = pk.u;
        }
    }
    __syncthreads();

    int w = t >> 6;
    int l = t & 63;
    int lrow = l & 15;
    int g = l >> 4;
    f32x4 acc[2][8] = {};
    int arow0 = w * 32 + lrow;
    int arow1 = arow0 + 16;
#pragma unroll
    for (int ks = 0; ks < 8; ++ks) {
        int kb = ks * 32 + g * 8;
        f16x4 a0 = *(const f16x4*)(Ab + ((arow0 * 256 + kb) ^ ((arow0 & 7) << 4)));
        f16x4 a1 = *(const f16x4*)(Ab + ((arow1 * 256 + kb) ^ ((arow1 & 7) << 4)));
#pragma unroll
        for (int nj = 0; nj < 8; ++nj) {
            int bc = nj * 16 + lrow;
            f16x4 b = *(const f16x4*)(Bb + ((bc * 256 + kb) ^ ((bc & 7) << 4)));
            acc[0][nj] = __builtin_amdgcn_mfma_f32_16x16x16f16(a0, b, acc[0][nj], 0, 0, 0);
            acc[1][nj] = __builtin_amdgcn_mfma_f32_16x16x16f16(a1, b, acc[1][nj], 0, 0, 0);
        }
    }
    // epilogue: scale by dinv[row], store fp16 into chunk (nj>>1), col (nj&1)*16+lrow
#pragma unroll
    for (int mi = 0; mi < 2; ++mi) {
        int rbase = br + w * 32 + mi * 16 + g * 4;
#pragma unroll
        for (int r = 0; r < 4; ++r) {
            int gr = rbase + r;
            if (gr < N) {
                float sc = dinv[gr];
#pragma unroll
                for (int nj = 0; nj < 8; ++nj) {
                    size_t idx = (size_t)(nj >> 1) * N * 32 + (size_t)gr * 32
                               + (nj & 1) * 16 + lrow;
                    h[idx] = __float2half(acc[mi][nj][r] * sc);
                }
            }
        }
    }
}

// ------ aggregation (chunked): relu(dinv[i]*(sum h'[s] + h'[i]) + bias) ------
// chunk = (blockIdx&7)>>1  -> XCD-pinned: each XCD's L2 sees one 3.2MB chunk.
// 4 lanes/node x uint4 (8 halves): 64 nodes per 256-thr block; unroll 8.
__device__ __forceinline__ void acc_row(uint4 u, float* a) {
    float2 q;
    q = __half22float2(*(const __half2*)&u.x); a[0] += q.x; a[1] += q.y;
    q = __half22float2(*(const __half2*)&u.y); a[2] += q.x; a[3] += q.y;
    q = __half22float2(*(const __half2*)&u.z); a[4] += q.x; a[5] += q.y;
    q = __half22float2(*(const __half2*)&u.w); a[6] += q.x; a[7] += q.y;
}

template<int WRITE_F32>
__global__ __launch_bounds__(256) void k_agg(const __half* __restrict__ h,
        const int* __restrict__ row_start, const unsigned short* __restrict__ deg,
        const int* __restrict__ esrc, const float* __restrict__ dinv,
        const float* __restrict__ bias, float* __restrict__ out,
        __half* __restrict__ act, int N) {
    int xcd   = blockIdx.x & 7;
    int chunk = xcd >> 1;
    int rank  = ((blockIdx.x >> 3) << 1) + (xcd & 1);   // 0..2K-1 within chunk
    int node = rank * 64 + (threadIdx.x >> 2);
    int l4 = threadIdx.x & 3;
    if (node >= N) return;
    float di = dinv[node];
    const uint4* hv = (const uint4*)(h + (size_t)chunk * N * 32);  // 4 uint4 per node-row
    int j0 = row_start[node];
    int j1 = j0 + deg[node];

    float a[8] = {};
    acc_row(hv[(size_t)node * 4 + l4], a);   // self-loop h'[node]

    int j = j0;
    for (; j + 8 <= j1; j += 8) {
        int s0 = esrc[j],     s1 = esrc[j + 1], s2 = esrc[j + 2], s3 = esrc[j + 3];
        int s4 = esrc[j + 4], s5 = esrc[j + 5], s6 = esrc[j + 6], s7 = esrc[j + 7];
        uint4 u0 = hv[(size_t)s0 * 4 + l4];
        uint4 u1 = hv[(size_t)s1 * 4 + l4];
        uint4 u2 = hv[(size_t)s2 * 4 + l4];
        uint4 u3 = hv[(size_t)s3 * 4 + l4];
        uint4 u4 = hv[(size_t)s4 * 4 + l4];
        uint4 u5 = hv[(size_t)s5 * 4 + l4];
        uint4 u6 = hv[(size_t)s6 * 4 + l4];
        uint4 u7 = hv[(size_t)s7 * 4 + l4];
        acc_row(u0, a); acc_row(u1, a); acc_row(u2, a); acc_row(u3, a);
        acc_row(u4, a); acc_row(u5, a); acc_row(u6, a); acc_row(u7, a);
    }
    for (; j + 4 <= j1; j += 4) {
        int s0 = esrc[j], s1 = esrc[j + 1], s2 = esrc[j + 2], s3 = esrc[j + 3];
        uint4 u0 = hv[(size_t)s0 * 4 + l4];
        uint4 u1 = hv[(size_t)s1 * 4 + l4];
        uint4 u2 = hv[(size_t)s2 * 4 + l4];
        uint4 u3 = hv[(size_t)s3 * 4 + l4];
        acc_row(u0, a); acc_row(u1, a); acc_row(u2, a); acc_row(u3, a);
    }
    for (; j < j1; ++j) {
        acc_row(hv[(size_t)esrc[j] * 4 + l4], a);
    }
    const float4* b4 = (const float4*)bias;
    float4 bv0 = b4[chunk * 8 + l4 * 2], bv1 = b4[chunk * 8 + l4 * 2 + 1];
    float o[8];
    o[0] = fmaxf(fmaf(a[0], di, bv0.x), 0.f);
    o[1] = fmaxf(fmaf(a[1], di, bv0.y), 0.f);
    o[2] = fmaxf(fmaf(a[2], di, bv0.z), 0.f);
    o[3] = fmaxf(fmaf(a[3], di, bv0.w), 0.f);
    o[4] = fmaxf(fmaf(a[4], di, bv1.x), 0.f);
    o[5] = fmaxf(fmaf(a[5], di, bv1.y), 0.f);
    o[6] = fmaxf(fmaf(a[6], di, bv1.z), 0.f);
    o[7] = fmaxf(fmaf(a[7], di, bv1.w), 0.f);
    if (WRITE_F32) {
        float4* o4 = (float4*)out;   // row-major final output, 32-col slice
        o4[(size_t)node * 32 + chunk * 8 + l4 * 2]     = make_float4(o[0], o[1], o[2], o[3]);
        o4[(size_t)node * 32 + chunk * 8 + l4 * 2 + 1] = make_float4(o[4], o[5], o[6], o[7]);
    } else {
        union { __half2 h2[4]; uint4 u; } pk;
        pk.h2[0] = __floats2half2_rn(o[0], o[1]);
        pk.h2[1] = __floats2half2_rn(o[2], o[3]);
        pk.h2[2] = __floats2half2_rn(o[4], o[5]);
        pk.h2[3] = __floats2half2_rn(o[6], o[7]);
        ((uint4*)act)[(size_t)chunk * N * 4 + (size_t)node * 4 + l4] = pk.u;  // chunked act
    }
}

// ---------------- host launch ----------------
extern "C" void kernel_launch(void* const* d_in, const int* in_sizes, int n_in,
                              void* d_out, int out_size, void* d_ws, size_t ws_size,
                              hipStream_t stream) {
    const float* x  = (const float*)d_in[0];
    const void*  ei = d_in[1];
    const float* W0 = (const float*)d_in[2];
    const float* b0 = (const float*)d_in[3];
    const float* W1 = (const float*)d_in[4];
    const float* b1 = (const float*)d_in[5];
    const float* W2 = (const float*)d_in[6];
    const float* b2 = (const float*)d_in[7];
    float* out = (float*)d_out;

    const int N = in_sizes[0] / D;       // 50000
    const int E = in_sizes[1] / 2;       // 800000

    char* ws = (char*)d_ws;
    size_t off = 0;
    auto alloc = [&](size_t bytes) {
        char* p = ws + off;
        off = (off + bytes + 255) & ~(size_t)255;
        return p;
    };
    int*            flag      = (int*)alloc(4);
    int*            bcur      = (int*)alloc(256 * 4);
    int*            row_start = (int*)alloc((size_t)N * 4);
    unsigned short* deg       = (unsigned short*)alloc((size_t)N * 2);
    float*          dinv      = (float*)alloc((size_t)N * 4);
    int*            esrc      = (int*)alloc((size_t)256 * CAP * 4);
    __half*         hbuf      = (__half*)alloc((size_t)N * D * 2);   // chunked [4][N][32]
    __half*         act       = (__half*)alloc((size_t)N * D * 2);   // chunked [4][N][32]
    __half*         Wt        = (__half*)alloc((size_t)3 * D * D * 2);
    // ebuck (196*CAP*8B = 9.6MB) aliases hbuf (12.8MB): graph build completes
    // before the first GEMM writes hbuf, stream-ordered.
    int2*           ebuck     = (int2*)hbuf;
    (void)ws_size;

    const int nbuck = (N + 255) >> 8;        // 196
    const int nbin  = (E + BIN_CH - 1) / BIN_CH;

    // init (detect + bcur bases + W prep) -> binning -> bucket build
    k_init<<<49, 256, 0, stream>>>((const int*)ei, W0, W1, W2, flag, bcur, Wt);
    k_binning<<<nbin, 256, 0, stream>>>(ei, E, flag, bcur, ebuck);
    k_bucket_build<<<nbuck, 256, 0, stream>>>(ebuck, bcur, row_start, deg, dinv, esrc, N);

    const int gemm_grid = (N + 127) / 128;           // 391
    const int ranks     = (N + 63) / 64;             // 782 (64 nodes/block)
    const int aggB      = (((ranks + 1) / 2)) * 8;   // 8 XCD groups x K

    // layer 0: x(f32) -> hbuf -> act(fp16)
    k_gemm_mfma<false><<<gemm_grid, 256, 0, stream>>>(x, Wt, dinv, hbuf, N);
    k_agg<0><<<aggB, 256, 0, stream>>>(hbuf, row_start, deg, esrc, dinv, b0, out, act, N);
    // layer 1: act -> hbuf -> act
    k_gemm_mfma<true><<<gemm_grid, 256, 0, stream>>>(act, Wt + (size_t)D * D, dinv, hbuf, N);
    k_agg<0><<<aggB, 256, 0, stream>>>(hbuf, row_start, deg, esrc, dinv, b1, out, act, N);
    // layer 2: act -> hbuf -> out(f32)
    k_gemm_mfma<true><<<gemm_grid, 256, 0, stream>>>(act, Wt + (size_t)2 * D * D, dinv, hbuf, N);
    k_agg<1><<<aggB, 256, 0, stream>>>(hbuf, row_start, deg, esrc, dinv, b2, out, act, N);
}